// Round 6
// baseline (2485.726 us; speedup 1.0000x reference)
//
#include <hip/hip_runtime.h>
#include <hip/hip_bf16.h>

constexpr int B = 32, N = 1024, C = 512, K = 4096, SN = 11;
constexpr long BCN = (long)B * N * C;  // 16,777,216
constexpr int TKC = 128;               // keys per flash chunk
constexpr int NCH = K / TKC;           // 32 chunks
constexpr float PSCALE = 256.f;        // p' = PSCALE*(p-1) stored in fp8
constexpr int SCONE = 0x7f7f7f7f;      // e8m0 scale 1.0 in every byte

typedef __attribute__((ext_vector_type(4))) float f32x4;
typedef __attribute__((ext_vector_type(16))) float f32x16;
typedef __attribute__((ext_vector_type(8))) int i32x8;
typedef __attribute__((ext_vector_type(4))) int i32x4;
typedef unsigned int u32;
typedef unsigned long u64;

static __device__ __forceinline__ short f2bf(float x) {
  __hip_bfloat16 h = __float2bfloat16(x);
  short s;
  __builtin_memcpy(&s, &h, sizeof(s));
  return s;
}
static __device__ __forceinline__ float bf2f(short s) {
  u32 u = ((u32)(unsigned short)s) << 16;
  float f;
  __builtin_memcpy(&f, &u, 4);
  return f;
}
static __device__ __forceinline__ u32 pk4_fp8(float a, float b, float c, float d) {
  int r = __builtin_amdgcn_cvt_pk_fp8_f32(a, b, 0, false);
  r = __builtin_amdgcn_cvt_pk_fp8_f32(c, d, r, true);
  return (u32)r;
}
static __device__ __forceinline__ f32x16 zero16() {
  f32x16 z;
#pragma unroll
  for (int i = 0; i < 16; ++i) z[i] = 0.f;
  return z;
}

// ---------------------------------------------------------------------------
// w_sq[k] = sum_c W[k,c]^2  (fp32 W — enters d exactly)
__global__ __launch_bounds__(256) void wsq_kernel(const float* __restrict__ W,
                                                  float* __restrict__ wsq) {
  __shared__ float red[256];
  int k = blockIdx.x;
  const float* row = W + (long)k * C;
  float s = 0.f;
  for (int c = threadIdx.x; c < C; c += 256) {
    float v = row[c];
    s += v * v;
  }
  red[threadIdx.x] = s;
  __syncthreads();
  for (int off = 128; off > 0; off >>= 1) {
    if (threadIdx.x < off) red[threadIdx.x] += red[threadIdx.x + off];
    __syncthreads();
  }
  if (threadIdx.x == 0) wsq[k] = red[0];
}

// csum[ch][c] = sum over the chunk's 128 keys of W[k][c] (fp32, for the p' trick)
__global__ __launch_bounds__(256) void colsum_kernel(const float* __restrict__ W,
                                                     float* __restrict__ csum) {
  int ch = blockIdx.x;
  const float* base = W + (long)ch * TKC * C;
  float s0 = 0.f, s1 = 0.f;
  for (int k = 0; k < TKC; ++k) {
    s0 += base[(long)k * C + threadIdx.x];
    s1 += base[(long)k * C + threadIdx.x + 256];
  }
  csum[ch * C + threadIdx.x] = s0;
  csum[ch * C + threadIdx.x + 256] = s1;
}

// ---------------------------------------------------------------------------
// fp8 fragment-packed W for mfma_scale_f32_32x32x64_f8f6f4 (2KB lane-linear
// units = unit*2048 + lane*32 bytes):
//  WnA (phase-1 A / keys x C):  unit u = t*8+cc  : lane L byte j holds
//     W[t*32+(L&31)][cc*64+(L>>5)*32+j]            (t = key32 block 0..127)
//  WtB (phase-2 B / keys x C):  unit u = f2*16+c2: lane L byte j holds
//     W[f2*64+(L>>5)*32+j][c2*32+(L&31)]           (f2 = key64 block 0..63)
// One block per 32 keys; 128 blocks.
__global__ __launch_bounds__(256) void prep_w(const float* __restrict__ W,
                                              unsigned char* __restrict__ WnA,
                                              unsigned char* __restrict__ WtB) {
  __shared__ __attribute__((aligned(16))) unsigned char tile[32 * 520];  // [key][c]
  const int blk = blockIdx.x, tid = threadIdx.x;
  const float* src = W + (long)blk * 32 * C;
#pragma unroll
  for (int i = 0; i < 16; ++i) {
    int idx = tid + i * 256;  // 4096 float4 groups
    float4 v = ((const float4*)src)[idx];
    int key = idx >> 7, c = (idx & 127) * 4;
    *(u32*)&tile[key * 520 + c] = pk4_fp8(v.x, v.y, v.z, v.w);
  }
  __syncthreads();
  // WnA units for t = blk (8 units, 64 lanes each -> 512 slots of 32B)
#pragma unroll
  for (int i = 0; i < 2; ++i) {
    int slot = tid + i * 256;
    int cc = slot >> 6, L = slot & 63;
    const unsigned char* sp = &tile[(L & 31) * 520 + cc * 64 + (L >> 5) * 32];
    u64* dst = (u64*)(WnA + ((long)(blk * 8 + cc) * 64 + L) * 32);
    dst[0] = *(const u64*)(sp);
    dst[1] = *(const u64*)(sp + 8);
    dst[2] = *(const u64*)(sp + 16);
    dst[3] = *(const u64*)(sp + 24);
  }
  // WtB half-units: f2 = blk>>1, h = blk&1 provides lanes with (L>>5)==h
#pragma unroll
  for (int i = 0; i < 2; ++i) {
    int slot = tid + i * 256;  // c2 = slot>>5 (0..15), rho = slot&31
    int c2 = slot >> 5, rho = slot & 31;
    union { unsigned char v[32]; u64 q[4]; } t;
#pragma unroll
    for (int j = 0; j < 32; ++j) t.v[j] = tile[j * 520 + c2 * 32 + rho];
    u64* dst = (u64*)(WtB + ((long)((blk >> 1) * 16 + c2) * 64 + (blk & 1) * 32 + rho) * 32);
    dst[0] = t.q[0]; dst[1] = t.q[1]; dst[2] = t.q[2]; dst[3] = t.q[3];
  }
}

// ---------------------------------------------------------------------------
// f (fp32) -> fbf (bf16) + gran-16 partial sums for the pn=1 z.
__global__ __launch_bounds__(256) void init_f(const float* __restrict__ f,
                                              short* __restrict__ fbf,
                                              float* __restrict__ zpart) {
  int b = blockIdx.x >> 5;
  int n0 = (blockIdx.x & 31) * 32 + (threadIdx.x >> 7) * 16;
  int c4 = threadIdx.x & 127;
  float ax = 0, ay = 0, az = 0, aw = 0;
  for (int j = 0; j < 16; ++j) {
    long e = ((long)b * N + n0 + j) * 128 + c4;
    float4 v = ((const float4*)f)[e];
    short4 o = {f2bf(v.x), f2bf(v.y), f2bf(v.z), f2bf(v.w)};
    ((short4*)fbf)[e] = o;
    ax += v.x; ay += v.y; az += v.z; aw += v.w;
  }
  float4 zp = {ax, ay, az, aw};
  ((float4*)zpart)[((long)b * 64 + (n0 >> 4)) * 128 + c4] = zp;
}

// zpart (gran-16 sums, [B][64][C] fp32) -> z fp8 at pn<=32 rows (mean over bs).
__global__ __launch_bounds__(256) void reduce_zpart(const float* __restrict__ zpart,
                                                    unsigned char* __restrict__ zq, int pn) {
  long idx = (long)blockIdx.x * 256 + threadIdx.x;
  long tot = (long)B * pn * 128;
  if (idx >= tot) return;
  int c4 = (int)(idx & 127);
  long row = idx >> 7;
  int b = (int)(row / pn), j = (int)(row % pn);
  int r = 64 / pn;
  float ax = 0, ay = 0, az = 0, aw = 0;
  for (int i = 0; i < r; ++i) {
    float4 v = ((const float4*)zpart)[((long)b * 64 + j * r + i) * 128 + c4];
    ax += v.x; ay += v.y; az += v.z; aw += v.w;
  }
  float inv = (float)pn / (float)N;
  *(u32*)&zq[row * C + c4 * 4] = pk4_fp8(ax * inv, ay * inv, az * inv, aw * inv);
}

// ---------------------------------------------------------------------------
// fp8 MX-MFMA (32x32x64) flash, 128 z-rows per 512-thread/8-wave block.
// Halves W-fragment L2 traffic per FLOP vs the 64-row tile and doubles MFMA
// work per serial softmax segment. WnA staged through LDS (single-buffered,
// reg-staged prefetch hidden under softmax). 2 soft barriers (lgkm-only) per
// chunk. STATIC 144KB LDS (graph-capture-safe; no hipFuncSetAttribute).
// Wave roles: phase-1 (kg=w&3 key32-group, zp=w>>2 row-pair) -> s0,s1;
// phase-2: all 4 row-tiles x C-slice c2 in {2w, 2w+1} -> hacc[4][2].
// p' = PSCALE*(exp(wsq-2s)-1) in fp8; H = sum(csum) + H'/PSCALE.
__global__ __launch_bounds__(512, 2) void flash_mfma(
    const unsigned char* __restrict__ zq, const unsigned char* __restrict__ WnA,
    const unsigned char* __restrict__ WtB, const float* __restrict__ wsq,
    const float* __restrict__ csum, short* __restrict__ hb,
    float* __restrict__ lpart, int M, int KS) {
  __shared__ __attribute__((aligned(16))) unsigned char lds[147456];
  unsigned char* ZS = lds;             // 64KB: 32 units, u = zt*8+cc
  unsigned char* WA = lds + 65536;     // 64KB: 32 units, u = kg*8+cc
  unsigned char* PS = lds + 131072;    // 16KB: 8 units,  u = rowtile*2+f
  const int tid = threadIdx.x;
  const int w = tid >> 6, lane = tid & 63;
  const int rho = lane & 31, hi = lane >> 5;
  const int kg = w & 3, zp = w >> 2;
  const long row0 = (long)blockIdx.x * 128;
  const int nc = NCH / KS, ch0 = blockIdx.y * nc;

  // stage Z (fp8) into B-frag units: unit u = zt*8+cc, lane L byte j holds
  // Z[row0+zt*32+(L&31)][cc*64+(L>>5)*32+j]  (zero-pad rows >= M)
#pragma unroll
  for (int i = 0; i < 4; ++i) {
    int u = w * 4 + i, zt = u >> 3, cc = u & 7;
    long row = row0 + zt * 32 + rho;
    u64 v0 = 0, v1 = 0, v2 = 0, v3 = 0;
    if (row < M) {
      const u64* sp = (const u64*)(zq + row * C + cc * 64 + hi * 32);
      v0 = sp[0]; v1 = sp[1]; v2 = sp[2]; v3 = sp[3];
    }
    u64* dp = (u64*)(ZS + u * 2048 + lane * 32);
    dp[0] = v0; dp[1] = v1; dp[2] = v2; dp[3] = v3;
  }
  // stage WA for chunk ch0 (contiguous 64KB copy)
  {
    const i32x4* gsrc = (const i32x4*)(WnA + (long)ch0 * 65536);
#pragma unroll
    for (int i = 0; i < 8; ++i) {
      i32x4 v = gsrc[tid + i * 512];
      *(i32x4*)(WA + (tid + i * 512) * 16) = v;
    }
  }
  f32x16 hacc[4][2];
#pragma unroll
  for (int zt = 0; zt < 4; ++zt) {
    hacc[zt][0] = zero16();
    hacc[zt][1] = zero16();
  }
  float lreg[2] = {0.f, 0.f};
  float cs[2] = {0.f, 0.f};
  __syncthreads();

#pragma unroll 1
  for (int ci = 0; ci < nc; ++ci) {
    const int ch = ch0 + ci;
    cs[0] += csum[ch * C + (2 * w) * 32 + rho];
    cs[1] += csum[ch * C + (2 * w + 1) * 32 + rho];
    // phase 1: S^T(32 keys x 64 rows of this zp-pair) = W.Z^T
    f32x16 s0 = zero16(), s1 = zero16();
    const unsigned char* wa = WA + kg * 8 * 2048 + lane * 32;
    const unsigned char* zb = ZS + zp * 16 * 2048 + lane * 32;
#pragma unroll
    for (int cc = 0; cc < 8; ++cc) {
      i32x8 a = *(const i32x8*)(wa + cc * 2048);
      i32x8 b0 = *(const i32x8*)(zb + cc * 2048);
      i32x8 b1 = *(const i32x8*)(zb + (8 + cc) * 2048);
      s0 = __builtin_amdgcn_mfma_scale_f32_32x32x64_f8f6f4(a, b0, s0, 0, 0, 0, SCONE, 0, SCONE);
      s1 = __builtin_amdgcn_mfma_scale_f32_32x32x64_f8f6f4(a, b1, s1, 0, 0, 0, SCONE, 0, SCONE);
    }
    // prefetch phase-2 WtB f=0 (stays in flight across barriers)
    const unsigned char* wb = WtB + ((long)(ch * 2) * 16 + 2 * w) * 2048 + lane * 32;
    i32x8 wb00 = *(const i32x8*)(wb);
    i32x8 wb01 = *(const i32x8*)(wb + 2048);
    // issue next chunk's WA stage loads (regs); write after barrier A
    const bool have_next = (ci + 1 < nc);
    i32x4 st[8];
    if (have_next) {
      const i32x4* gsrc = (const i32x4*)(WnA + (long)(ch + 1) * 65536);
#pragma unroll
      for (int i = 0; i < 8; ++i) st[i] = gsrc[tid + i * 512];
    }
    // soft barrier A: all waves done reading WA(ci) / P(ci-1)
    asm volatile("s_waitcnt lgkmcnt(0)" ::: "memory");
    __builtin_amdgcn_s_barrier();
    // softmax: keys kg*32 + kappa(r,hi); rows (2zp+ztl)*32 + rho
    const float* wsb = wsq + ch * TKC + kg * 32 + hi * 4;
    float wv[16];
#pragma unroll
    for (int g = 0; g < 4; ++g) {
      float4 t = *(const float4*)(wsb + 8 * g);
      wv[4 * g + 0] = t.x; wv[4 * g + 1] = t.y; wv[4 * g + 2] = t.z; wv[4 * g + 3] = t.w;
    }
    const int pbase = (kg & 1) * 1024 + rho * 32 + hi * 4;
    {  // ztl = 0
      float sum = 0.f, pv[16];
#pragma unroll
      for (int r = 0; r < 16; ++r) {
        float e = __expf(wv[r] - 2.f * s0[r]);
        sum += e;
        pv[r] = PSCALE * e - PSCALE;
      }
      lreg[0] += sum;
      unsigned char* Pun = PS + ((2 * zp) * 2 + (kg >> 1)) * 2048;
#pragma unroll
      for (int g = 0; g < 4; ++g)
        *(u32*)(Pun + pbase + 8 * g) =
            pk4_fp8(pv[4 * g], pv[4 * g + 1], pv[4 * g + 2], pv[4 * g + 3]);
    }
    // write staged WA(ci+1) (loads' latency hidden under ztl=0 softmax)
    if (have_next) {
#pragma unroll
      for (int i = 0; i < 8; ++i)
        *(i32x4*)(WA + (tid + i * 512) * 16) = st[i];
    }
    {  // ztl = 1
      float sum = 0.f, pv[16];
#pragma unroll
      for (int r = 0; r < 16; ++r) {
        float e = __expf(wv[r] - 2.f * s1[r]);
        sum += e;
        pv[r] = PSCALE * e - PSCALE;
      }
      lreg[1] += sum;
      unsigned char* Pun = PS + ((2 * zp + 1) * 2 + (kg >> 1)) * 2048;
#pragma unroll
      for (int g = 0; g < 4; ++g)
        *(u32*)(Pun + pbase + 8 * g) =
            pk4_fp8(pv[4 * g], pv[4 * g + 1], pv[4 * g + 2], pv[4 * g + 3]);
    }
    // soft barrier B: P + WA(ci+1) LDS writes drained; VMEM stays in flight
    asm volatile("s_waitcnt lgkmcnt(0)" ::: "memory");
    __builtin_amdgcn_s_barrier();
    __builtin_amdgcn_sched_barrier(0);
    // phase 2: H'(128 rows x 64c-slice) += P'.W
#pragma unroll
    for (int f = 0; f < 2; ++f) {
      const unsigned char* Pf = PS + f * 2048 + lane * 32;
      i32x8 pa[4];
#pragma unroll
      for (int zt = 0; zt < 4; ++zt) pa[zt] = *(const i32x8*)(Pf + zt * 4096);
      i32x8 bw0, bw1;
      if (f == 0) {
        bw0 = wb00;
        bw1 = wb01;
      } else {
        bw0 = *(const i32x8*)(wb + 16 * 2048);
        bw1 = *(const i32x8*)(wb + 17 * 2048);
      }
#pragma unroll
      for (int zt = 0; zt < 4; ++zt) {
        hacc[zt][0] = __builtin_amdgcn_mfma_scale_f32_32x32x64_f8f6f4(pa[zt], bw0, hacc[zt][0], 0, 0, 0, SCONE, 0, SCONE);
        hacc[zt][1] = __builtin_amdgcn_mfma_scale_f32_32x32x64_f8f6f4(pa[zt], bw1, hacc[zt][1], 0, 0, 0, SCONE, 0, SCONE);
      }
    }
  }
  // cross-wave l reduction: l4[row_local 128][kg 4] in PS (phase-2 reads done)
  __syncthreads();
  lreg[0] += __shfl_xor(lreg[0], 32);
  lreg[1] += __shfl_xor(lreg[1], 32);
  float* l4 = (float*)PS;
  if (hi == 0) {
    l4[((2 * zp) * 32 + rho) * 4 + kg] = lreg[0];
    l4[((2 * zp + 1) * 32 + rho) * 4 + kg] = lreg[1];
  }
  __syncthreads();
  constexpr float PINV = 1.f / PSCALE;
  if (KS == 1) {
#pragma unroll
    for (int zt = 0; zt < 4; ++zt)
#pragma unroll
      for (int r = 0; r < 16; ++r) {
        int rl = zt * 32 + (r & 3) + 8 * (r >> 2) + 4 * hi;
        long row = row0 + rl;
        if (row < M) {
          float4 lv = ((const float4*)l4)[rl];
          float inv = 1.f / (lv.x + lv.y + lv.z + lv.w);
          hb[row * C + (2 * w) * 32 + rho] = f2bf((cs[0] + hacc[zt][0][r] * PINV) * inv);
          hb[row * C + (2 * w + 1) * 32 + rho] = f2bf((cs[1] + hacc[zt][1][r] * PINV) * inv);
        }
      }
  } else {
    long base = (long)blockIdx.y * M * C;
#pragma unroll
    for (int zt = 0; zt < 4; ++zt)
#pragma unroll
      for (int r = 0; r < 16; ++r) {
        int rl = zt * 32 + (r & 3) + 8 * (r >> 2) + 4 * hi;
        long row = row0 + rl;
        if (row < M) {
          hb[base + row * C + (2 * w) * 32 + rho] = f2bf(cs[0] + hacc[zt][0][r] * PINV);
          hb[base + row * C + (2 * w + 1) * 32 + rho] = f2bf(cs[1] + hacc[zt][1][r] * PINV);
        }
      }
    if (tid < 128) {
      long row = row0 + tid;
      if (row < M) {
        float4 lv = ((const float4*)l4)[tid];
        lpart[(long)blockIdx.y * M + row] = lv.x + lv.y + lv.z + lv.w;
      }
    }
  }
}

// ---------------------------------------------------------------------------
// In-place: hb[m][c] = (sum_s hpart[s][m][c]) / (sum_s lpart[s][m]).
__global__ __launch_bounds__(256) void combine_kernel(short* __restrict__ hb,
                                                      const float* __restrict__ lpart,
                                                      int M, int KS) {
  long idx = (long)blockIdx.x * 256 + threadIdx.x;
  long tot = (long)M * 128;  // short4 groups
  if (idx >= tot) return;
  int m = (int)(idx >> 7);
  float lsum = 0.f;
  for (int s = 0; s < KS; ++s) lsum += lpart[(long)s * M + m];
  float ax = 0, ay = 0, az = 0, aw = 0;
  for (int s = 0; s < KS; ++s) {
    short4 v = ((const short4*)hb)[(long)s * tot + idx];
    ax += bf2f(v.x); ay += bf2f(v.y); az += bf2f(v.z); aw += bf2f(v.w);
  }
  float inv = 1.f / lsum;
  short4 o = {f2bf(ax * inv), f2bf(ay * inv), f2bf(az * inv), f2bf(aw * inv)};
  ((short4*)hb)[idx] = o;
}

// ---------------------------------------------------------------------------
// Fused: fhat += upsample(h); loss; emit next-scale z (fp8 direct if
// pn_next>=64, else gran-16 fp32 partials). Last scale writes fp32 d_out.
__global__ __launch_bounds__(256) void fused_up(
    const short* __restrict__ hb, const short* __restrict__ fbf,
    const short* fhin, short* fhout, float* __restrict__ outf,
    unsigned char* __restrict__ zq, float* __restrict__ zpart,
    double* __restrict__ accum, int pn, int pn_next, int first, int last) {
  const int b = blockIdx.x >> 5;
  const int n0 = (blockIdx.x & 31) * 32 + (threadIdx.x >> 7) * 16;
  const int c4 = threadIdx.x & 127;
  const float scale = (float)pn * (1.f / (float)N);
  const int bs_next = pn_next ? (N / pn_next) : 0;
  float zx = 0, zy = 0, zz = 0, zw = 0, part = 0.f;
  for (int j = 0; j < 16; ++j) {
    int n = n0 + j;
    long e = ((long)b * N + n) * 128 + c4;
    float coords = ((float)n + 0.5f) * scale - 0.5f;
    coords = fminf(fmaxf(coords, 0.f), (float)(pn - 1));
    int i0 = (int)coords;
    int i1 = min(i0 + 1, pn - 1);
    float wq = coords - (float)i0, ow = 1.f - wq;
    short4 h0 = ((const short4*)hb)[((long)b * pn + i0) * 128 + c4];
    short4 h1 = ((const short4*)hb)[((long)b * pn + i1) * 128 + c4];
    short4 fv = ((const short4*)fbf)[e];
    float fhx, fhy, fhz, fhw;
    if (first) {
      fhx = fhy = fhz = fhw = 0.f;
    } else {
      short4 p = ((const short4*)fhin)[e];
      fhx = bf2f(p.x); fhy = bf2f(p.y); fhz = bf2f(p.z); fhw = bf2f(p.w);
    }
    fhx += bf2f(h0.x) * ow + bf2f(h1.x) * wq;
    fhy += bf2f(h0.y) * ow + bf2f(h1.y) * wq;
    fhz += bf2f(h0.z) * ow + bf2f(h1.z) * wq;
    fhw += bf2f(h0.w) * ow + bf2f(h1.w) * wq;
    if (last) {
      float4 o = {fhx, fhy, fhz, fhw};
      ((float4*)outf)[e] = o;
    } else {
      short4 o = {f2bf(fhx), f2bf(fhy), f2bf(fhz), f2bf(fhw)};
      ((short4*)fhout)[e] = o;
    }
    float dx = fhx - bf2f(fv.x), dy = fhy - bf2f(fv.y);
    float dz = fhz - bf2f(fv.z), dw = fhw - bf2f(fv.w);
    part += dx * dx + dy * dy + dz * dz + dw * dw;
    zx -= dx; zy -= dy; zz -= dz; zw -= dw;
    if (pn_next >= 64) {
      if (((n + 1) & (bs_next - 1)) == 0) {
        float inv = 1.f / (float)bs_next;
        *(u32*)&zq[((long)b * pn_next + n / bs_next) * C + c4 * 4] =
            pk4_fp8(zx * inv, zy * inv, zz * inv, zw * inv);
        zx = zy = zz = zw = 0.f;
      }
    }
  }
  if (pn_next && pn_next < 64) {
    float4 zp = {zx, zy, zz, zw};
    ((float4*)zpart)[((long)b * 64 + (n0 >> 4)) * 128 + c4] = zp;
  }
  __shared__ float red[256];
  red[threadIdx.x] = part;
  __syncthreads();
  for (int off = 128; off > 0; off >>= 1) {
    if (threadIdx.x < off) red[threadIdx.x] += red[threadIdx.x + off];
    __syncthreads();
  }
  if (threadIdx.x == 0) atomicAdd(&accum[blockIdx.x & 255], (double)red[0]);
}

// ---------------------------------------------------------------------------
__global__ void finalize_kernel(const double* __restrict__ accum,
                                float* __restrict__ out_scalars) {
  if (threadIdx.x == 0 && blockIdx.x == 0) {
    double s = 0.0;
    for (int i = 0; i < 256; ++i) s += accum[i];
    double denom = (double)SN * (double)BCN;
    out_scalars[0] = (float)(0.25 * s / denom);  // commit
    out_scalars[1] = (float)(s / denom);         // qlat
  }
}

// ---------------------------------------------------------------------------
extern "C" void kernel_launch(void* const* d_in, const int* in_sizes, int n_in,
                              void* d_out, int out_size, void* d_ws, size_t ws_size,
                              hipStream_t stream) {
  const float* f = (const float*)d_in[0];  // (B,N,C) fp32
  const float* W = (const float*)d_in[1];  // (K,C)  fp32
  float* out = (float*)d_out;

  const long MBy = 1l << 20;
  char* ws = (char*)d_ws;
  short* hb = (short*)ws;                              // 32 MB (h / bf16 partials)
  short* fbf = (short*)(ws + 32 * MBy);                // 32 MB
  short* fhbf = (short*)(ws + 64 * MBy);               // 32 MB
  unsigned char* zq = (unsigned char*)(ws + 96 * MBy); // 16 MB
  unsigned char* WnA = (unsigned char*)(ws + 112 * MBy);  // 2 MB
  unsigned char* WtB = (unsigned char*)(ws + 114 * MBy);  // 2 MB
  float* zpart = (float*)(ws + 116 * MBy);             // 4 MB region (uses 2)
  float* wsqf = (float*)(ws + 120 * MBy);              // 16 KB
  float* csum = (float*)(ws + 120 * MBy + (1l << 16)); // 64 KB
  float* lpart = (float*)(ws + 120 * MBy + (1l << 17)); // 128 KB
  double* accum = (double*)(ws + 121 * MBy);           // 2 KB

  hipMemsetAsync(accum, 0, 256 * sizeof(double), stream);

  wsq_kernel<<<K, 256, 0, stream>>>(W, wsqf);
  colsum_kernel<<<NCH, 256, 0, stream>>>(W, csum);
  prep_w<<<K / 32, 256, 0, stream>>>(W, WnA, WtB);
  init_f<<<B * 32, 256, 0, stream>>>(f, fbf, zpart);
  reduce_zpart<<<(B * 128 + 255) / 256, 256, 0, stream>>>(zpart, zq, 1);

  for (int s = 0; s < SN; ++s) {
    int pn = 1 << s;
    int M = B * pn;
    int gx = (M + 127) / 128;     // 128 rows per block
    int KS = 256 / gx;            // target 256 blocks = 1 per CU
    if (KS < 1) KS = 1;
    if (KS > 32) KS = 32;
    flash_mfma<<<dim3(gx, KS), 512, 0, stream>>>(zq, WnA, WtB, wsqf, csum, hb, lpart, M, KS);
    if (KS > 1)
      combine_kernel<<<(int)(((long)M * 128 + 255) / 256), 256, 0, stream>>>(hb, lpart, M, KS);
    int pn_next = (s < SN - 1) ? (pn << 1) : 0;
    fused_up<<<B * 32, 256, 0, stream>>>(hb, fbf, fhbf, fhbf, out, zq, zpart, accum,
                                         pn, pn_next, s == 0 ? 1 : 0, s == SN - 1 ? 1 : 0);
    if (pn_next && pn_next < 64)
      reduce_zpart<<<(int)(((long)B * pn_next * 128 + 255) / 256), 256, 0, stream>>>(zpart, zq, pn_next);
  }

  finalize_kernel<<<1, 64, 0, stream>>>(accum, out + BCN);
}

// Round 7
// 2176.313 us; speedup vs baseline: 1.1422x; 1.1422x over previous
//
#include <hip/hip_runtime.h>
#include <hip/hip_bf16.h>

constexpr int B = 32, N = 1024, C = 512, K = 4096, SN = 11;
constexpr long BCN = (long)B * N * C;  // 16,777,216
constexpr int TKC = 128;               // keys per flash chunk
constexpr int NCH = K / TKC;           // 32 chunks
constexpr float PSCALE = 256.f;        // p' = PSCALE*(p-1) stored in fp8
constexpr int SCONE = 0x7f7f7f7f;      // e8m0 scale 1.0 in every byte

typedef __attribute__((ext_vector_type(4))) float f32x4;
typedef __attribute__((ext_vector_type(16))) float f32x16;
typedef __attribute__((ext_vector_type(8))) int i32x8;
typedef __attribute__((ext_vector_type(4))) int i32x4;
typedef unsigned int u32;
typedef unsigned long u64;

static __device__ __forceinline__ short f2bf(float x) {
  __hip_bfloat16 h = __float2bfloat16(x);
  short s;
  __builtin_memcpy(&s, &h, sizeof(s));
  return s;
}
static __device__ __forceinline__ float bf2f(short s) {
  u32 u = ((u32)(unsigned short)s) << 16;
  float f;
  __builtin_memcpy(&f, &u, 4);
  return f;
}
static __device__ __forceinline__ u32 pk4_fp8(float a, float b, float c, float d) {
  int r = __builtin_amdgcn_cvt_pk_fp8_f32(a, b, 0, false);
  r = __builtin_amdgcn_cvt_pk_fp8_f32(c, d, r, true);
  return (u32)r;
}
static __device__ __forceinline__ f32x16 zero16() {
  f32x16 z;
#pragma unroll
  for (int i = 0; i < 16; ++i) z[i] = 0.f;
  return z;
}

// ---------------------------------------------------------------------------
// w_sq[k] = sum_c W[k,c]^2  (fp32 W — enters d exactly)
__global__ __launch_bounds__(256) void wsq_kernel(const float* __restrict__ W,
                                                  float* __restrict__ wsq) {
  __shared__ float red[256];
  int k = blockIdx.x;
  const float* row = W + (long)k * C;
  float s = 0.f;
  for (int c = threadIdx.x; c < C; c += 256) {
    float v = row[c];
    s += v * v;
  }
  red[threadIdx.x] = s;
  __syncthreads();
  for (int off = 128; off > 0; off >>= 1) {
    if (threadIdx.x < off) red[threadIdx.x] += red[threadIdx.x + off];
    __syncthreads();
  }
  if (threadIdx.x == 0) wsq[k] = red[0];
}

// csum[ch][c] = sum over the chunk's 128 keys of W[k][c] (fp32, for the p' trick)
__global__ __launch_bounds__(256) void colsum_kernel(const float* __restrict__ W,
                                                     float* __restrict__ csum) {
  int ch = blockIdx.x;
  const float* base = W + (long)ch * TKC * C;
  float s0 = 0.f, s1 = 0.f;
  for (int k = 0; k < TKC; ++k) {
    s0 += base[(long)k * C + threadIdx.x];
    s1 += base[(long)k * C + threadIdx.x + 256];
  }
  csum[ch * C + threadIdx.x] = s0;
  csum[ch * C + threadIdx.x + 256] = s1;
}

// ---------------------------------------------------------------------------
// fp8 fragment-packed W for mfma_scale_f32_32x32x64_f8f6f4 (2KB lane-linear
// units = unit*2048 + lane*32 bytes):
//  WnA (phase-1 A / keys x C):  unit u = t*8+cc  : lane L byte j holds
//     W[t*32+(L&31)][cc*64+(L>>5)*32+j]            (t = key32 block 0..127)
//  WtB (phase-2 B / keys x C):  unit u = f2*16+c2: lane L byte j holds
//     W[f2*64+(L>>5)*32+j][c2*32+(L&31)]           (f2 = key64 block 0..63)
// One block per 32 keys; 128 blocks.
__global__ __launch_bounds__(256) void prep_w(const float* __restrict__ W,
                                              unsigned char* __restrict__ WnA,
                                              unsigned char* __restrict__ WtB) {
  __shared__ __attribute__((aligned(16))) unsigned char tile[32 * 520];  // [key][c]
  const int blk = blockIdx.x, tid = threadIdx.x;
  const float* src = W + (long)blk * 32 * C;
#pragma unroll
  for (int i = 0; i < 16; ++i) {
    int idx = tid + i * 256;  // 4096 float4 groups
    float4 v = ((const float4*)src)[idx];
    int key = idx >> 7, c = (idx & 127) * 4;
    *(u32*)&tile[key * 520 + c] = pk4_fp8(v.x, v.y, v.z, v.w);
  }
  __syncthreads();
  // WnA units for t = blk (8 units, 64 lanes each -> 512 slots of 32B)
#pragma unroll
  for (int i = 0; i < 2; ++i) {
    int slot = tid + i * 256;
    int cc = slot >> 6, L = slot & 63;
    const unsigned char* sp = &tile[(L & 31) * 520 + cc * 64 + (L >> 5) * 32];
    u64* dst = (u64*)(WnA + ((long)(blk * 8 + cc) * 64 + L) * 32);
    dst[0] = *(const u64*)(sp);
    dst[1] = *(const u64*)(sp + 8);
    dst[2] = *(const u64*)(sp + 16);
    dst[3] = *(const u64*)(sp + 24);
  }
  // WtB half-units: f2 = blk>>1, h = blk&1 provides lanes with (L>>5)==h
#pragma unroll
  for (int i = 0; i < 2; ++i) {
    int slot = tid + i * 256;  // c2 = slot>>5 (0..15), rho = slot&31
    int c2 = slot >> 5, rho = slot & 31;
    union { unsigned char v[32]; u64 q[4]; } t;
#pragma unroll
    for (int j = 0; j < 32; ++j) t.v[j] = tile[j * 520 + c2 * 32 + rho];
    u64* dst = (u64*)(WtB + ((long)((blk >> 1) * 16 + c2) * 64 + (blk & 1) * 32 + rho) * 32);
    dst[0] = t.q[0]; dst[1] = t.q[1]; dst[2] = t.q[2]; dst[3] = t.q[3];
  }
}

// ---------------------------------------------------------------------------
// f (fp32) -> fbf (bf16) + gran-16 partial sums for the pn=1 z.
__global__ __launch_bounds__(256) void init_f(const float* __restrict__ f,
                                              short* __restrict__ fbf,
                                              float* __restrict__ zpart) {
  int b = blockIdx.x >> 5;
  int n0 = (blockIdx.x & 31) * 32 + (threadIdx.x >> 7) * 16;
  int c4 = threadIdx.x & 127;
  float ax = 0, ay = 0, az = 0, aw = 0;
  for (int j = 0; j < 16; ++j) {
    long e = ((long)b * N + n0 + j) * 128 + c4;
    float4 v = ((const float4*)f)[e];
    short4 o = {f2bf(v.x), f2bf(v.y), f2bf(v.z), f2bf(v.w)};
    ((short4*)fbf)[e] = o;
    ax += v.x; ay += v.y; az += v.z; aw += v.w;
  }
  float4 zp = {ax, ay, az, aw};
  ((float4*)zpart)[((long)b * 64 + (n0 >> 4)) * 128 + c4] = zp;
}

// zpart (gran-16 sums, [B][64][C] fp32) -> z fp8 at pn<=32 rows (mean over bs).
__global__ __launch_bounds__(256) void reduce_zpart(const float* __restrict__ zpart,
                                                    unsigned char* __restrict__ zq, int pn) {
  long idx = (long)blockIdx.x * 256 + threadIdx.x;
  long tot = (long)B * pn * 128;
  if (idx >= tot) return;
  int c4 = (int)(idx & 127);
  long row = idx >> 7;
  int b = (int)(row / pn), j = (int)(row % pn);
  int r = 64 / pn;
  float ax = 0, ay = 0, az = 0, aw = 0;
  for (int i = 0; i < r; ++i) {
    float4 v = ((const float4*)zpart)[((long)b * 64 + j * r + i) * 128 + c4];
    ax += v.x; ay += v.y; az += v.z; aw += v.w;
  }
  float inv = (float)pn / (float)N;
  *(u32*)&zq[row * C + c4 * 4] = pk4_fp8(ax * inv, ay * inv, az * inv, aw * inv);
}

// ---------------------------------------------------------------------------
// fp8 MX-MFMA (32x32x64) flash, 128 z-rows per 512-thread/8-wave block.
// Same dataflow/addressing as the (numerically verified) R6 kernel, but on a
// strict register diet to fit the 256 unified-reg/wave budget (8-wave block
// forces 2 waves/SIMD): compact fused softmax (no wv/pv arrays), WA staging
// split into 2 rounds of st[4]. hacc[4][2] lives in AGPRs (128).
// 2 lgkm-only soft barriers per chunk; WtB f=0 prefetched across them.
__global__ __launch_bounds__(512, 2) void flash_mfma(
    const unsigned char* __restrict__ zq, const unsigned char* __restrict__ WnA,
    const unsigned char* __restrict__ WtB, const float* __restrict__ wsq,
    const float* __restrict__ csum, short* __restrict__ hb,
    float* __restrict__ lpart, int M, int KS) {
  __shared__ __attribute__((aligned(16))) unsigned char lds[147456];
  unsigned char* ZS = lds;             // 64KB: 32 units, u = zt*8+cc
  unsigned char* WA = lds + 65536;     // 64KB: 32 units, u = kg*8+cc
  unsigned char* PS = lds + 131072;    // 16KB: 8 units,  u = rowtile*2+f
  const int tid = threadIdx.x;
  const int w = tid >> 6, lane = tid & 63;
  const int rho = lane & 31, hi = lane >> 5;
  const int kg = w & 3, zp = w >> 2;
  const long row0 = (long)blockIdx.x * 128;
  const int nc = NCH / KS, ch0 = blockIdx.y * nc;

  // stage Z (fp8) into B-frag units: unit u = zt*8+cc, lane L byte j holds
  // Z[row0+zt*32+(L&31)][cc*64+(L>>5)*32+j]  (zero-pad rows >= M)
#pragma unroll
  for (int i = 0; i < 4; ++i) {
    int u = w * 4 + i, zt = u >> 3, cc = u & 7;
    long row = row0 + zt * 32 + rho;
    u64 v0 = 0, v1 = 0, v2 = 0, v3 = 0;
    if (row < M) {
      const u64* sp = (const u64*)(zq + row * C + cc * 64 + hi * 32);
      v0 = sp[0]; v1 = sp[1]; v2 = sp[2]; v3 = sp[3];
    }
    u64* dp = (u64*)(ZS + u * 2048 + lane * 32);
    dp[0] = v0; dp[1] = v1; dp[2] = v2; dp[3] = v3;
  }
  // stage WA for chunk ch0 (contiguous 64KB copy)
  {
    const i32x4* gsrc = (const i32x4*)(WnA + (long)ch0 * 65536);
#pragma unroll
    for (int i = 0; i < 8; ++i) {
      i32x4 v = gsrc[tid + i * 512];
      *(i32x4*)(WA + (tid + i * 512) * 16) = v;
    }
  }
  f32x16 hacc[4][2];
#pragma unroll
  for (int zt = 0; zt < 4; ++zt) {
    hacc[zt][0] = zero16();
    hacc[zt][1] = zero16();
  }
  float lreg[2] = {0.f, 0.f};
  float cs[2] = {0.f, 0.f};
  __syncthreads();

#pragma unroll 1
  for (int ci = 0; ci < nc; ++ci) {
    const int ch = ch0 + ci;
    cs[0] += csum[ch * C + (2 * w) * 32 + rho];
    cs[1] += csum[ch * C + (2 * w + 1) * 32 + rho];
    // phase 1: S^T(32 keys x 64 rows of this zp-pair) = W.Z^T
    f32x16 s0 = zero16(), s1 = zero16();
    {
      const unsigned char* wa = WA + kg * 8 * 2048 + lane * 32;
      const unsigned char* zb = ZS + zp * 16 * 2048 + lane * 32;
#pragma unroll
      for (int cc = 0; cc < 8; ++cc) {
        i32x8 a = *(const i32x8*)(wa + cc * 2048);
        i32x8 b0 = *(const i32x8*)(zb + cc * 2048);
        i32x8 b1 = *(const i32x8*)(zb + (8 + cc) * 2048);
        s0 = __builtin_amdgcn_mfma_scale_f32_32x32x64_f8f6f4(a, b0, s0, 0, 0, 0, SCONE, 0, SCONE);
        s1 = __builtin_amdgcn_mfma_scale_f32_32x32x64_f8f6f4(a, b1, s1, 0, 0, 0, SCONE, 0, SCONE);
      }
    }
    // prefetch phase-2 WtB f=0 (stays in flight / in regs across barriers)
    const unsigned char* wb = WtB + ((long)(ch * 2) * 16 + 2 * w) * 2048 + lane * 32;
    i32x8 wb00 = *(const i32x8*)(wb);
    i32x8 wb01 = *(const i32x8*)(wb + 2048);
    // round-1 WA stage loads for next chunk (written after barrier A)
    const bool have_next = (ci + 1 < nc);
    const i32x4* gnext = (const i32x4*)(WnA + (long)(ch + 1) * 65536);
    i32x4 st[4];
    if (have_next) {
#pragma unroll
      for (int i = 0; i < 4; ++i) st[i] = gnext[tid + i * 512];
    }
    // soft barrier A: all waves done reading WA(ci) / P(ci-1)
    asm volatile("s_waitcnt lgkmcnt(0)" ::: "memory");
    __builtin_amdgcn_s_barrier();
    // softmax (compact, fused): keys kg*32 + kappa(r,hi); rows (2zp+ztl)*32+rho
    const float* wsb = wsq + ch * TKC + kg * 32 + hi * 4;
    const int pbase = (kg & 1) * 1024 + rho * 32 + hi * 4;
    {  // ztl = 0
      float sum = 0.f;
      unsigned char* Pun = PS + ((2 * zp) * 2 + (kg >> 1)) * 2048;
#pragma unroll
      for (int g = 0; g < 4; ++g) {
        float4 t = *(const float4*)(wsb + 8 * g);
        float e0 = __expf(t.x - 2.f * s0[4 * g + 0]);
        float e1 = __expf(t.y - 2.f * s0[4 * g + 1]);
        float e2 = __expf(t.z - 2.f * s0[4 * g + 2]);
        float e3 = __expf(t.w - 2.f * s0[4 * g + 3]);
        sum += (e0 + e1) + (e2 + e3);
        *(u32*)(Pun + pbase + 8 * g) =
            pk4_fp8(PSCALE * e0 - PSCALE, PSCALE * e1 - PSCALE,
                    PSCALE * e2 - PSCALE, PSCALE * e3 - PSCALE);
      }
      lreg[0] += sum;
    }
    // write round-1 WA(ci+1); issue round-2 loads (hidden under ztl=1 softmax)
    if (have_next) {
#pragma unroll
      for (int i = 0; i < 4; ++i) *(i32x4*)(WA + (tid + i * 512) * 16) = st[i];
#pragma unroll
      for (int i = 0; i < 4; ++i) st[i] = gnext[tid + (4 + i) * 512];
    }
    {  // ztl = 1
      float sum = 0.f;
      unsigned char* Pun = PS + ((2 * zp + 1) * 2 + (kg >> 1)) * 2048;
#pragma unroll
      for (int g = 0; g < 4; ++g) {
        float4 t = *(const float4*)(wsb + 8 * g);
        float e0 = __expf(t.x - 2.f * s1[4 * g + 0]);
        float e1 = __expf(t.y - 2.f * s1[4 * g + 1]);
        float e2 = __expf(t.z - 2.f * s1[4 * g + 2]);
        float e3 = __expf(t.w - 2.f * s1[4 * g + 3]);
        sum += (e0 + e1) + (e2 + e3);
        *(u32*)(Pun + pbase + 8 * g) =
            pk4_fp8(PSCALE * e0 - PSCALE, PSCALE * e1 - PSCALE,
                    PSCALE * e2 - PSCALE, PSCALE * e3 - PSCALE);
      }
      lreg[1] += sum;
    }
    // write round-2 WA(ci+1)
    if (have_next) {
#pragma unroll
      for (int i = 0; i < 4; ++i) *(i32x4*)(WA + (tid + (4 + i) * 512) * 16) = st[i];
    }
    // soft barrier B: P + WA(ci+1) LDS writes drained; VMEM stays in flight
    asm volatile("s_waitcnt lgkmcnt(0)" ::: "memory");
    __builtin_amdgcn_s_barrier();
    __builtin_amdgcn_sched_barrier(0);
    // phase 2: H'(128 rows x 64c-slice) += P'.W
#pragma unroll
    for (int f = 0; f < 2; ++f) {
      const unsigned char* Pf = PS + f * 2048 + lane * 32;
      i32x8 pa[4];
#pragma unroll
      for (int zt = 0; zt < 4; ++zt) pa[zt] = *(const i32x8*)(Pf + zt * 4096);
      i32x8 bw0, bw1;
      if (f == 0) {
        bw0 = wb00;
        bw1 = wb01;
      } else {
        bw0 = *(const i32x8*)(wb + 16 * 2048);
        bw1 = *(const i32x8*)(wb + 17 * 2048);
      }
#pragma unroll
      for (int zt = 0; zt < 4; ++zt) {
        hacc[zt][0] = __builtin_amdgcn_mfma_scale_f32_32x32x64_f8f6f4(pa[zt], bw0, hacc[zt][0], 0, 0, 0, SCONE, 0, SCONE);
        hacc[zt][1] = __builtin_amdgcn_mfma_scale_f32_32x32x64_f8f6f4(pa[zt], bw1, hacc[zt][1], 0, 0, 0, SCONE, 0, SCONE);
      }
    }
  }
  // cross-wave l reduction: l4[row_local 128][kg 4] in PS (phase-2 reads done)
  __syncthreads();
  lreg[0] += __shfl_xor(lreg[0], 32);
  lreg[1] += __shfl_xor(lreg[1], 32);
  float* l4 = (float*)PS;
  if (hi == 0) {
    l4[((2 * zp) * 32 + rho) * 4 + kg] = lreg[0];
    l4[((2 * zp + 1) * 32 + rho) * 4 + kg] = lreg[1];
  }
  __syncthreads();
  constexpr float PINV = 1.f / PSCALE;
  if (KS == 1) {
#pragma unroll
    for (int zt = 0; zt < 4; ++zt)
#pragma unroll
      for (int r = 0; r < 16; ++r) {
        int rl = zt * 32 + (r & 3) + 8 * (r >> 2) + 4 * hi;
        long row = row0 + rl;
        if (row < M) {
          float4 lv = ((const float4*)l4)[rl];
          float inv = 1.f / (lv.x + lv.y + lv.z + lv.w);
          hb[row * C + (2 * w) * 32 + rho] = f2bf((cs[0] + hacc[zt][0][r] * PINV) * inv);
          hb[row * C + (2 * w + 1) * 32 + rho] = f2bf((cs[1] + hacc[zt][1][r] * PINV) * inv);
        }
      }
  } else {
    long base = (long)blockIdx.y * M * C;
#pragma unroll
    for (int zt = 0; zt < 4; ++zt)
#pragma unroll
      for (int r = 0; r < 16; ++r) {
        int rl = zt * 32 + (r & 3) + 8 * (r >> 2) + 4 * hi;
        long row = row0 + rl;
        if (row < M) {
          hb[base + row * C + (2 * w) * 32 + rho] = f2bf(cs[0] + hacc[zt][0][r] * PINV);
          hb[base + row * C + (2 * w + 1) * 32 + rho] = f2bf(cs[1] + hacc[zt][1][r] * PINV);
        }
      }
    if (tid < 128) {
      long row = row0 + tid;
      if (row < M) {
        float4 lv = ((const float4*)l4)[tid];
        lpart[(long)blockIdx.y * M + row] = lv.x + lv.y + lv.z + lv.w;
      }
    }
  }
}

// ---------------------------------------------------------------------------
// In-place: hb[m][c] = (sum_s hpart[s][m][c]) / (sum_s lpart[s][m]).
__global__ __launch_bounds__(256) void combine_kernel(short* __restrict__ hb,
                                                      const float* __restrict__ lpart,
                                                      int M, int KS) {
  long idx = (long)blockIdx.x * 256 + threadIdx.x;
  long tot = (long)M * 128;  // short4 groups
  if (idx >= tot) return;
  int m = (int)(idx >> 7);
  float lsum = 0.f;
  for (int s = 0; s < KS; ++s) lsum += lpart[(long)s * M + m];
  float ax = 0, ay = 0, az = 0, aw = 0;
  for (int s = 0; s < KS; ++s) {
    short4 v = ((const short4*)hb)[(long)s * tot + idx];
    ax += bf2f(v.x); ay += bf2f(v.y); az += bf2f(v.z); aw += bf2f(v.w);
  }
  float inv = 1.f / lsum;
  short4 o = {f2bf(ax * inv), f2bf(ay * inv), f2bf(az * inv), f2bf(aw * inv)};
  ((short4*)hb)[idx] = o;
}

// ---------------------------------------------------------------------------
// Fused: fhat += upsample(h); loss; emit next-scale z (fp8 direct if
// pn_next>=64, else gran-16 fp32 partials). Last scale writes fp32 d_out.
__global__ __launch_bounds__(256) void fused_up(
    const short* __restrict__ hb, const short* __restrict__ fbf,
    const short* fhin, short* fhout, float* __restrict__ outf,
    unsigned char* __restrict__ zq, float* __restrict__ zpart,
    double* __restrict__ accum, int pn, int pn_next, int first, int last) {
  const int b = blockIdx.x >> 5;
  const int n0 = (blockIdx.x & 31) * 32 + (threadIdx.x >> 7) * 16;
  const int c4 = threadIdx.x & 127;
  const float scale = (float)pn * (1.f / (float)N);
  const int bs_next = pn_next ? (N / pn_next) : 0;
  float zx = 0, zy = 0, zz = 0, zw = 0, part = 0.f;
  for (int j = 0; j < 16; ++j) {
    int n = n0 + j;
    long e = ((long)b * N + n) * 128 + c4;
    float coords = ((float)n + 0.5f) * scale - 0.5f;
    coords = fminf(fmaxf(coords, 0.f), (float)(pn - 1));
    int i0 = (int)coords;
    int i1 = min(i0 + 1, pn - 1);
    float wq = coords - (float)i0, ow = 1.f - wq;
    short4 h0 = ((const short4*)hb)[((long)b * pn + i0) * 128 + c4];
    short4 h1 = ((const short4*)hb)[((long)b * pn + i1) * 128 + c4];
    short4 fv = ((const short4*)fbf)[e];
    float fhx, fhy, fhz, fhw;
    if (first) {
      fhx = fhy = fhz = fhw = 0.f;
    } else {
      short4 p = ((const short4*)fhin)[e];
      fhx = bf2f(p.x); fhy = bf2f(p.y); fhz = bf2f(p.z); fhw = bf2f(p.w);
    }
    fhx += bf2f(h0.x) * ow + bf2f(h1.x) * wq;
    fhy += bf2f(h0.y) * ow + bf2f(h1.y) * wq;
    fhz += bf2f(h0.z) * ow + bf2f(h1.z) * wq;
    fhw += bf2f(h0.w) * ow + bf2f(h1.w) * wq;
    if (last) {
      float4 o = {fhx, fhy, fhz, fhw};
      ((float4*)outf)[e] = o;
    } else {
      short4 o = {f2bf(fhx), f2bf(fhy), f2bf(fhz), f2bf(fhw)};
      ((short4*)fhout)[e] = o;
    }
    float dx = fhx - bf2f(fv.x), dy = fhy - bf2f(fv.y);
    float dz = fhz - bf2f(fv.z), dw = fhw - bf2f(fv.w);
    part += dx * dx + dy * dy + dz * dz + dw * dw;
    zx -= dx; zy -= dy; zz -= dz; zw -= dw;
    if (pn_next >= 64) {
      if (((n + 1) & (bs_next - 1)) == 0) {
        float inv = 1.f / (float)bs_next;
        *(u32*)&zq[((long)b * pn_next + n / bs_next) * C + c4 * 4] =
            pk4_fp8(zx * inv, zy * inv, zz * inv, zw * inv);
        zx = zy = zz = zw = 0.f;
      }
    }
  }
  if (pn_next && pn_next < 64) {
    float4 zp = {zx, zy, zz, zw};
    ((float4*)zpart)[((long)b * 64 + (n0 >> 4)) * 128 + c4] = zp;
  }
  __shared__ float red[256];
  red[threadIdx.x] = part;
  __syncthreads();
  for (int off = 128; off > 0; off >>= 1) {
    if (threadIdx.x < off) red[threadIdx.x] += red[threadIdx.x + off];
    __syncthreads();
  }
  if (threadIdx.x == 0) atomicAdd(&accum[blockIdx.x & 255], (double)red[0]);
}

// ---------------------------------------------------------------------------
__global__ void finalize_kernel(const double* __restrict__ accum,
                                float* __restrict__ out_scalars) {
  if (threadIdx.x == 0 && blockIdx.x == 0) {
    double s = 0.0;
    for (int i = 0; i < 256; ++i) s += accum[i];
    double denom = (double)SN * (double)BCN;
    out_scalars[0] = (float)(0.25 * s / denom);  // commit
    out_scalars[1] = (float)(s / denom);         // qlat
  }
}

// ---------------------------------------------------------------------------
extern "C" void kernel_launch(void* const* d_in, const int* in_sizes, int n_in,
                              void* d_out, int out_size, void* d_ws, size_t ws_size,
                              hipStream_t stream) {
  const float* f = (const float*)d_in[0];  // (B,N,C) fp32
  const float* W = (const float*)d_in[1];  // (K,C)  fp32
  float* out = (float*)d_out;

  const long MBy = 1l << 20;
  char* ws = (char*)d_ws;
  short* hb = (short*)ws;                              // 32 MB (h / bf16 partials)
  short* fbf = (short*)(ws + 32 * MBy);                // 32 MB
  short* fhbf = (short*)(ws + 64 * MBy);               // 32 MB
  unsigned char* zq = (unsigned char*)(ws + 96 * MBy); // 16 MB
  unsigned char* WnA = (unsigned char*)(ws + 112 * MBy);  // 2 MB
  unsigned char* WtB = (unsigned char*)(ws + 114 * MBy);  // 2 MB
  float* zpart = (float*)(ws + 116 * MBy);             // 4 MB region (uses 2)
  float* wsqf = (float*)(ws + 120 * MBy);              // 16 KB
  float* csum = (float*)(ws + 120 * MBy + (1l << 16)); // 64 KB
  float* lpart = (float*)(ws + 120 * MBy + (1l << 17)); // 128 KB
  double* accum = (double*)(ws + 121 * MBy);           // 2 KB

  hipMemsetAsync(accum, 0, 256 * sizeof(double), stream);

  wsq_kernel<<<K, 256, 0, stream>>>(W, wsqf);
  colsum_kernel<<<NCH, 256, 0, stream>>>(W, csum);
  prep_w<<<K / 32, 256, 0, stream>>>(W, WnA, WtB);
  init_f<<<B * 32, 256, 0, stream>>>(f, fbf, zpart);
  reduce_zpart<<<(B * 128 + 255) / 256, 256, 0, stream>>>(zpart, zq, 1);

  for (int s = 0; s < SN; ++s) {
    int pn = 1 << s;
    int M = B * pn;
    int gx = (M + 127) / 128;     // 128 rows per block
    int KS = 256 / gx;            // target 256 blocks = 1 per CU
    if (KS < 1) KS = 1;
    if (KS > 32) KS = 32;
    flash_mfma<<<dim3(gx, KS), 512, 0, stream>>>(zq, WnA, WtB, wsqf, csum, hb, lpart, M, KS);
    if (KS > 1)
      combine_kernel<<<(int)(((long)M * 128 + 255) / 256), 256, 0, stream>>>(hb, lpart, M, KS);
    int pn_next = (s < SN - 1) ? (pn << 1) : 0;
    fused_up<<<B * 32, 256, 0, stream>>>(hb, fbf, fhbf, fhbf, out, zq, zpart, accum,
                                         pn, pn_next, s == 0 ? 1 : 0, s == SN - 1 ? 1 : 0);
    if (pn_next && pn_next < 64)
      reduce_zpart<<<(int)(((long)B * pn_next * 128 + 255) / 256), 256, 0, stream>>>(zpart, zq, pn_next);
  }

  finalize_kernel<<<1, 64, 0, stream>>>(accum, out + BCN);
}

// Round 8
// 1028.409 us; speedup vs baseline: 2.4171x; 2.1162x over previous
//
#include <hip/hip_runtime.h>
#include <hip/hip_bf16.h>

constexpr int B = 32, N = 1024, C = 512, K = 4096, SN = 11;
constexpr long BCN = (long)B * N * C;  // 16,777,216
constexpr int TKC = 128;               // keys per flash chunk
constexpr int NCH = K / TKC;           // 32 chunks
constexpr float PSCALE = 256.f;        // p' = PSCALE*(p-1) stored in fp8
constexpr int SCONE = 0x7f7f7f7f;      // e8m0 scale 1.0 in every byte

typedef __attribute__((ext_vector_type(4))) float f32x4;
typedef __attribute__((ext_vector_type(16))) float f32x16;
typedef __attribute__((ext_vector_type(8))) int i32x8;
typedef __attribute__((ext_vector_type(4))) int i32x4;
typedef unsigned int u32;
typedef unsigned long u64;

static __device__ __forceinline__ short f2bf(float x) {
  __hip_bfloat16 h = __float2bfloat16(x);
  short s;
  __builtin_memcpy(&s, &h, sizeof(s));
  return s;
}
static __device__ __forceinline__ float bf2f(short s) {
  u32 u = ((u32)(unsigned short)s) << 16;
  float f;
  __builtin_memcpy(&f, &u, 4);
  return f;
}
static __device__ __forceinline__ u32 pk4_fp8(float a, float b, float c, float d) {
  int r = __builtin_amdgcn_cvt_pk_fp8_f32(a, b, 0, false);
  r = __builtin_amdgcn_cvt_pk_fp8_f32(c, d, r, true);
  return (u32)r;
}
static __device__ __forceinline__ f32x16 zero16() {
  f32x16 z;
#pragma unroll
  for (int i = 0; i < 16; ++i) z[i] = 0.f;
  return z;
}

// ---------------------------------------------------------------------------
// w_sq[k] = sum_c W[k,c]^2  (fp32 W — enters d exactly)
__global__ __launch_bounds__(256) void wsq_kernel(const float* __restrict__ W,
                                                  float* __restrict__ wsq) {
  __shared__ float red[256];
  int k = blockIdx.x;
  const float* row = W + (long)k * C;
  float s = 0.f;
  for (int c = threadIdx.x; c < C; c += 256) {
    float v = row[c];
    s += v * v;
  }
  red[threadIdx.x] = s;
  __syncthreads();
  for (int off = 128; off > 0; off >>= 1) {
    if (threadIdx.x < off) red[threadIdx.x] += red[threadIdx.x + off];
    __syncthreads();
  }
  if (threadIdx.x == 0) wsq[k] = red[0];
}

// csum[ch][c] = sum over the chunk's 128 keys of W[k][c] (fp32, for the p' trick)
__global__ __launch_bounds__(256) void colsum_kernel(const float* __restrict__ W,
                                                     float* __restrict__ csum) {
  int ch = blockIdx.x;
  const float* base = W + (long)ch * TKC * C;
  float s0 = 0.f, s1 = 0.f;
  for (int k = 0; k < TKC; ++k) {
    s0 += base[(long)k * C + threadIdx.x];
    s1 += base[(long)k * C + threadIdx.x + 256];
  }
  csum[ch * C + threadIdx.x] = s0;
  csum[ch * C + threadIdx.x + 256] = s1;
}

// ---------------------------------------------------------------------------
// fp8 fragment-packed W for mfma_scale_f32_32x32x64_f8f6f4 (2KB lane-linear
// units = unit*2048 + lane*32 bytes):
//  WnA (phase-1 A / keys x C):  unit u = t*8+cc  : lane L byte j holds
//     W[t*32+(L&31)][cc*64+(L>>5)*32+j]            (t = key32 block 0..127)
//  WtB (phase-2 B / keys x C):  unit u = f2*16+c2: lane L byte j holds
//     W[f2*64+(L>>5)*32+j][c2*32+(L&31)]           (f2 = key64 block 0..63)
// One block per 32 keys; 128 blocks.
__global__ __launch_bounds__(256) void prep_w(const float* __restrict__ W,
                                              unsigned char* __restrict__ WnA,
                                              unsigned char* __restrict__ WtB) {
  __shared__ __attribute__((aligned(16))) unsigned char tile[32 * 520];  // [key][c]
  const int blk = blockIdx.x, tid = threadIdx.x;
  const float* src = W + (long)blk * 32 * C;
#pragma unroll
  for (int i = 0; i < 16; ++i) {
    int idx = tid + i * 256;  // 4096 float4 groups
    float4 v = ((const float4*)src)[idx];
    int key = idx >> 7, c = (idx & 127) * 4;
    *(u32*)&tile[key * 520 + c] = pk4_fp8(v.x, v.y, v.z, v.w);
  }
  __syncthreads();
  // WnA units for t = blk (8 units, 64 lanes each -> 512 slots of 32B)
#pragma unroll
  for (int i = 0; i < 2; ++i) {
    int slot = tid + i * 256;
    int cc = slot >> 6, L = slot & 63;
    const unsigned char* sp = &tile[(L & 31) * 520 + cc * 64 + (L >> 5) * 32];
    u64* dst = (u64*)(WnA + ((long)(blk * 8 + cc) * 64 + L) * 32);
    dst[0] = *(const u64*)(sp);
    dst[1] = *(const u64*)(sp + 8);
    dst[2] = *(const u64*)(sp + 16);
    dst[3] = *(const u64*)(sp + 24);
  }
  // WtB half-units: f2 = blk>>1, h = blk&1 provides lanes with (L>>5)==h
#pragma unroll
  for (int i = 0; i < 2; ++i) {
    int slot = tid + i * 256;  // c2 = slot>>5 (0..15), rho = slot&31
    int c2 = slot >> 5, rho = slot & 31;
    union { unsigned char v[32]; u64 q[4]; } t;
#pragma unroll
    for (int j = 0; j < 32; ++j) t.v[j] = tile[j * 520 + c2 * 32 + rho];
    u64* dst = (u64*)(WtB + ((long)((blk >> 1) * 16 + c2) * 64 + (blk & 1) * 32 + rho) * 32);
    dst[0] = t.q[0]; dst[1] = t.q[1]; dst[2] = t.q[2]; dst[3] = t.q[3];
  }
}

// ---------------------------------------------------------------------------
// f (fp32) -> fbf (bf16) + gran-16 partial sums for the pn=1 z.
__global__ __launch_bounds__(256) void init_f(const float* __restrict__ f,
                                              short* __restrict__ fbf,
                                              float* __restrict__ zpart) {
  int b = blockIdx.x >> 5;
  int n0 = (blockIdx.x & 31) * 32 + (threadIdx.x >> 7) * 16;
  int c4 = threadIdx.x & 127;
  float ax = 0, ay = 0, az = 0, aw = 0;
  for (int j = 0; j < 16; ++j) {
    long e = ((long)b * N + n0 + j) * 128 + c4;
    float4 v = ((const float4*)f)[e];
    short4 o = {f2bf(v.x), f2bf(v.y), f2bf(v.z), f2bf(v.w)};
    ((short4*)fbf)[e] = o;
    ax += v.x; ay += v.y; az += v.z; aw += v.w;
  }
  float4 zp = {ax, ay, az, aw};
  ((float4*)zpart)[((long)b * 64 + (n0 >> 4)) * 128 + c4] = zp;
}

// zpart (gran-16 sums, [B][64][C] fp32) -> z fp8 at pn<=32 rows (mean over bs).
__global__ __launch_bounds__(256) void reduce_zpart(const float* __restrict__ zpart,
                                                    unsigned char* __restrict__ zq, int pn) {
  long idx = (long)blockIdx.x * 256 + threadIdx.x;
  long tot = (long)B * pn * 128;
  if (idx >= tot) return;
  int c4 = (int)(idx & 127);
  long row = idx >> 7;
  int b = (int)(row / pn), j = (int)(row % pn);
  int r = 64 / pn;
  float ax = 0, ay = 0, az = 0, aw = 0;
  for (int i = 0; i < r; ++i) {
    float4 v = ((const float4*)zpart)[((long)b * 64 + j * r + i) * 128 + c4];
    ax += v.x; ay += v.y; az += v.z; aw += v.w;
  }
  float inv = (float)pn / (float)N;
  *(u32*)&zq[row * C + c4 * 4] = pk4_fp8(ax * inv, ay * inv, az * inv, aw * inv);
}

// ---------------------------------------------------------------------------
// fp8 MX-MFMA (32x32x64, unit scales) flash, inverted dataflow, 1 barrier per
// chunk (double-buffered P). 64 z-rows per 256-thread/4-wave block — the best
// measured tile (R1: 142us @ pn=1024; 32-row doubles W L2-traffic, 128-row
// spills). 2 independent blocks/CU phase-interleave (no shared barrier).
// vs R1: (a) csum accumulated in prologue (off the serial chunk chain);
// (b) s_setprio(1) around MFMA clusters (T5; regime = independent blocks).
// p' = PSCALE*(exp(wsq-2s)-1) in fp8; H = sum(csum) + H'/PSCALE.
__global__ __launch_bounds__(256, 2) void flash_mfma(
    const unsigned char* __restrict__ zq, const unsigned char* __restrict__ WnA,
    const unsigned char* __restrict__ WtB, const float* __restrict__ wsq,
    const float* __restrict__ csum, short* __restrict__ hb,
    float* __restrict__ lpart, int M, int KS) {
  __shared__ __attribute__((aligned(16))) unsigned char ZS[16 * 2048];      // 32KB
  __shared__ __attribute__((aligned(16))) unsigned char PS[2][4 * 2048];    // 2x8KB
  const int tid = threadIdx.x;
  const int w = tid >> 6, lane = tid & 63;
  const int rho = lane & 31, hi = lane >> 5;
  const long row0 = (long)blockIdx.x * 64;
  const int nc = NCH / KS, ch0 = blockIdx.y * nc;

  // stage Z (fp8) into 32x32x64 B-frag units: unit u = zt*8+cc, lane L byte j
  // holds Z[row0+zt*32+(L&31)][cc*64+(L>>5)*32+j]  (zero-pad rows >= M)
#pragma unroll
  for (int i = 0; i < 4; ++i) {
    int u = i * 4 + w, zt = u >> 3, cc = u & 7;
    long row = row0 + zt * 32 + rho;
    u64 v0 = 0, v1 = 0, v2 = 0, v3 = 0;
    if (row < M) {
      const u64* sp = (const u64*)(zq + row * C + cc * 64 + hi * 32);
      v0 = sp[0]; v1 = sp[1]; v2 = sp[2]; v3 = sp[3];
    }
    u64* dp = (u64*)(ZS + u * 2048 + lane * 32);
    dp[0] = v0; dp[1] = v1; dp[2] = v2; dp[3] = v3;
  }
  f32x16 hacc[2][4];
#pragma unroll
  for (int zt = 0; zt < 2; ++zt)
#pragma unroll
    for (int ct = 0; ct < 4; ++ct) hacc[zt][ct] = zero16();
  float lreg[2] = {0.f, 0.f};
  // csum accumulation hoisted out of the chunk loop (prologue, overlaps the
  // Z-staging barrier wait instead of sitting between MFMA phases)
  float cs[4] = {0.f, 0.f, 0.f, 0.f};
#pragma unroll 1
  for (int ci = 0; ci < nc; ++ci) {
    const float* cp = csum + (ch0 + ci) * C + w * 128;
#pragma unroll
    for (int ct = 0; ct < 4; ++ct) cs[ct] += cp[ct * 32 + rho];
  }
  __syncthreads();

#pragma unroll 1
  for (int ci = 0; ci < nc; ++ci) {
    const int ch = ch0 + ci;
    // phase 1: S^T(32 keys x 64 zrows) = W.Z^T ; keys = ch*128 + w*32 + [0,32)
    f32x16 s[2];
    s[0] = zero16();
    s[1] = zero16();
    const unsigned char* wa = WnA + ((long)(ch * 4 + w) * 8) * 2048 + lane * 32;
    const unsigned char* zb = ZS + lane * 32;
    __builtin_amdgcn_s_setprio(1);
#pragma unroll
    for (int cc = 0; cc < 8; ++cc) {
      i32x8 a = *(const i32x8*)(wa + cc * 2048);
      i32x8 b0 = *(const i32x8*)(zb + cc * 2048);
      i32x8 b1 = *(const i32x8*)(zb + (8 + cc) * 2048);
      s[0] = __builtin_amdgcn_mfma_scale_f32_32x32x64_f8f6f4(a, b0, s[0], 0, 0, 0, SCONE, 0, SCONE);
      s[1] = __builtin_amdgcn_mfma_scale_f32_32x32x64_f8f6f4(a, b1, s[1], 0, 0, 0, SCONE, 0, SCONE);
    }
    __builtin_amdgcn_s_setprio(0);
    // softmax weights: p'=PSCALE*(p-1) -> fp8 into PS[ci&1].
    // D mapping: key-in-wave kappa = (r&3)+8*(r>>2)+4*hi, zrow = rho.
    const float* wsb = wsq + ch * TKC + w * 32 + hi * 4;
    float wv[16];
#pragma unroll
    for (int g = 0; g < 4; ++g) {
      float4 t = *(const float4*)(wsb + 8 * g);
      wv[4 * g + 0] = t.x; wv[4 * g + 1] = t.y; wv[4 * g + 2] = t.z; wv[4 * g + 3] = t.w;
    }
    unsigned char* Pun = PS[ci & 1] + (w >> 1) * 2048;
    const int pbase = (w & 1) * 1024 + rho * 32 + hi * 4;
#pragma unroll
    for (int zt = 0; zt < 2; ++zt) {
      float sum = 0.f, pv[16];
#pragma unroll
      for (int r = 0; r < 16; ++r) {
        float e = __expf(wv[r] - 2.f * s[zt][r]);
        sum += e;
        pv[r] = PSCALE * e - PSCALE;
      }
      lreg[zt] += sum;
#pragma unroll
      for (int g = 0; g < 4; ++g) {
        u32 pk = pk4_fp8(pv[4 * g], pv[4 * g + 1], pv[4 * g + 2], pv[4 * g + 3]);
        *(u32*)(Pun + zt * 4096 + pbase + 8 * g) = pk;
      }
    }
    __syncthreads();  // single barrier per chunk (P double-buffered)
    // phase 2: H'(64 x 128c-slice) += P'.W ; W B-frags from L2
    const unsigned char* Pr = PS[ci & 1] + lane * 32;
    i32x8 pa[2][2];
#pragma unroll
    for (int zt = 0; zt < 2; ++zt)
#pragma unroll
      for (int f = 0; f < 2; ++f) pa[zt][f] = *(const i32x8*)(Pr + (zt * 2 + f) * 2048);
    const unsigned char* wb = WtB + ((long)(ch * 2) * 16 + w * 4) * 2048 + lane * 32;
    __builtin_amdgcn_s_setprio(1);
#pragma unroll
    for (int f = 0; f < 2; ++f)
#pragma unroll
      for (int ct = 0; ct < 4; ++ct) {
        i32x8 bw = *(const i32x8*)(wb + (f * 16 + ct) * 2048);
        hacc[0][ct] = __builtin_amdgcn_mfma_scale_f32_32x32x64_f8f6f4(pa[0][f], bw, hacc[0][ct], 0, 0, 0, SCONE, 0, SCONE);
        hacc[1][ct] = __builtin_amdgcn_mfma_scale_f32_32x32x64_f8f6f4(pa[1][f], bw, hacc[1][ct], 0, 0, 0, SCONE, 0, SCONE);
      }
    __builtin_amdgcn_s_setprio(0);
  }
  // cross-wave l reduction
  __syncthreads();
  lreg[0] += __shfl_xor(lreg[0], 32);
  lreg[1] += __shfl_xor(lreg[1], 32);
  float* l4 = (float*)PS;  // [64][4]
  if (hi == 0) {
    l4[rho * 4 + w] = lreg[0];
    l4[(32 + rho) * 4 + w] = lreg[1];
  }
  __syncthreads();
  constexpr float PINV = 1.f / PSCALE;
  if (KS == 1) {
#pragma unroll
    for (int zt = 0; zt < 2; ++zt)
#pragma unroll
      for (int r = 0; r < 16; ++r) {
        int rr = zt * 32 + (r & 3) + 8 * (r >> 2) + 4 * hi;
        long row = row0 + rr;
        if (row < M) {
          float4 lv = ((const float4*)l4)[rr];
          float inv = 1.f / (lv.x + lv.y + lv.z + lv.w);
#pragma unroll
          for (int ct = 0; ct < 4; ++ct)
            hb[row * C + (w * 8 + ct * 2) * 16 + 0] = hb[row * C + (w * 8 + ct * 2) * 16 + 0];  // no-op guard (kept layout below)
        }
      }
    // (actual write below — kept in one loop for clarity)
#pragma unroll
    for (int zt = 0; zt < 2; ++zt)
#pragma unroll
      for (int r = 0; r < 16; ++r) {
        int rr = zt * 32 + (r & 3) + 8 * (r >> 2) + 4 * hi;
        long row = row0 + rr;
        if (row < M) {
          float4 lv = ((const float4*)l4)[rr];
          float inv = 1.f / (lv.x + lv.y + lv.z + lv.w);
#pragma unroll
          for (int ct = 0; ct < 4; ++ct)
            hb[row * C + (w * 4 + ct) * 32 + rho] =
                f2bf((cs[ct] + hacc[zt][ct][r] * PINV) * inv);
        }
      }
  } else {
    long base = (long)blockIdx.y * M * C;
#pragma unroll
    for (int zt = 0; zt < 2; ++zt)
#pragma unroll
      for (int r = 0; r < 16; ++r) {
        int rr = zt * 32 + (r & 3) + 8 * (r >> 2) + 4 * hi;
        long row = row0 + rr;
        if (row < M) {
#pragma unroll
          for (int ct = 0; ct < 4; ++ct)
            hb[base + row * C + (w * 4 + ct) * 32 + rho] =
                f2bf(cs[ct] + hacc[zt][ct][r] * PINV);
        }
      }
    if (w == 0) {
      long row = row0 + lane;
      if (row < M) {
        float4 lv = ((const float4*)l4)[lane];
        lpart[(long)blockIdx.y * M + row] = lv.x + lv.y + lv.z + lv.w;
      }
    }
  }
}

// ---------------------------------------------------------------------------
// In-place: hb[m][c] = (sum_s hpart[s][m][c]) / (sum_s lpart[s][m]).
__global__ __launch_bounds__(256) void combine_kernel(short* __restrict__ hb,
                                                      const float* __restrict__ lpart,
                                                      int M, int KS) {
  long idx = (long)blockIdx.x * 256 + threadIdx.x;
  long tot = (long)M * 128;  // short4 groups
  if (idx >= tot) return;
  int m = (int)(idx >> 7);
  float lsum = 0.f;
  for (int s = 0; s < KS; ++s) lsum += lpart[(long)s * M + m];
  float ax = 0, ay = 0, az = 0, aw = 0;
  for (int s = 0; s < KS; ++s) {
    short4 v = ((const short4*)hb)[(long)s * tot + idx];
    ax += bf2f(v.x); ay += bf2f(v.y); az += bf2f(v.z); aw += bf2f(v.w);
  }
  float inv = 1.f / lsum;
  short4 o = {f2bf(ax * inv), f2bf(ay * inv), f2bf(az * inv), f2bf(aw * inv)};
  ((short4*)hb)[idx] = o;
}

// ---------------------------------------------------------------------------
// Fused: fhat += upsample(h); loss; emit next-scale z (fp8 direct if
// pn_next>=64, else gran-16 fp32 partials). Last scale writes fp32 d_out.
__global__ __launch_bounds__(256) void fused_up(
    const short* __restrict__ hb, const short* __restrict__ fbf,
    const short* fhin, short* fhout, float* __restrict__ outf,
    unsigned char* __restrict__ zq, float* __restrict__ zpart,
    double* __restrict__ accum, int pn, int pn_next, int first, int last) {
  const int b = blockIdx.x >> 5;
  const int n0 = (blockIdx.x & 31) * 32 + (threadIdx.x >> 7) * 16;
  const int c4 = threadIdx.x & 127;
  const float scale = (float)pn * (1.f / (float)N);
  const int bs_next = pn_next ? (N / pn_next) : 0;
  float zx = 0, zy = 0, zz = 0, zw = 0, part = 0.f;
  for (int j = 0; j < 16; ++j) {
    int n = n0 + j;
    long e = ((long)b * N + n) * 128 + c4;
    float coords = ((float)n + 0.5f) * scale - 0.5f;
    coords = fminf(fmaxf(coords, 0.f), (float)(pn - 1));
    int i0 = (int)coords;
    int i1 = min(i0 + 1, pn - 1);
    float wq = coords - (float)i0, ow = 1.f - wq;
    short4 h0 = ((const short4*)hb)[((long)b * pn + i0) * 128 + c4];
    short4 h1 = ((const short4*)hb)[((long)b * pn + i1) * 128 + c4];
    short4 fv = ((const short4*)fbf)[e];
    float fhx, fhy, fhz, fhw;
    if (first) {
      fhx = fhy = fhz = fhw = 0.f;
    } else {
      short4 p = ((const short4*)fhin)[e];
      fhx = bf2f(p.x); fhy = bf2f(p.y); fhz = bf2f(p.z); fhw = bf2f(p.w);
    }
    fhx += bf2f(h0.x) * ow + bf2f(h1.x) * wq;
    fhy += bf2f(h0.y) * ow + bf2f(h1.y) * wq;
    fhz += bf2f(h0.z) * ow + bf2f(h1.z) * wq;
    fhw += bf2f(h0.w) * ow + bf2f(h1.w) * wq;
    if (last) {
      float4 o = {fhx, fhy, fhz, fhw};
      ((float4*)outf)[e] = o;
    } else {
      short4 o = {f2bf(fhx), f2bf(fhy), f2bf(fhz), f2bf(fhw)};
      ((short4*)fhout)[e] = o;
    }
    float dx = fhx - bf2f(fv.x), dy = fhy - bf2f(fv.y);
    float dz = fhz - bf2f(fv.z), dw = fhw - bf2f(fv.w);
    part += dx * dx + dy * dy + dz * dz + dw * dw;
    zx -= dx; zy -= dy; zz -= dz; zw -= dw;
    if (pn_next >= 64) {
      if (((n + 1) & (bs_next - 1)) == 0) {
        float inv = 1.f / (float)bs_next;
        *(u32*)&zq[((long)b * pn_next + n / bs_next) * C + c4 * 4] =
            pk4_fp8(zx * inv, zy * inv, zz * inv, zw * inv);
        zx = zy = zz = zw = 0.f;
      }
    }
  }
  if (pn_next && pn_next < 64) {
    float4 zp = {zx, zy, zz, zw};
    ((float4*)zpart)[((long)b * 64 + (n0 >> 4)) * 128 + c4] = zp;
  }
  __shared__ float red[256];
  red[threadIdx.x] = part;
  __syncthreads();
  for (int off = 128; off > 0; off >>= 1) {
    if (threadIdx.x < off) red[threadIdx.x] += red[threadIdx.x + off];
    __syncthreads();
  }
  if (threadIdx.x == 0) atomicAdd(&accum[blockIdx.x & 255], (double)red[0]);
}

// ---------------------------------------------------------------------------
__global__ void finalize_kernel(const double* __restrict__ accum,
                                float* __restrict__ out_scalars) {
  if (threadIdx.x == 0 && blockIdx.x == 0) {
    double s = 0.0;
    for (int i = 0; i < 256; ++i) s += accum[i];
    double denom = (double)SN * (double)BCN;
    out_scalars[0] = (float)(0.25 * s / denom);  // commit
    out_scalars[1] = (float)(s / denom);         // qlat
  }
}

// ---------------------------------------------------------------------------
extern "C" void kernel_launch(void* const* d_in, const int* in_sizes, int n_in,
                              void* d_out, int out_size, void* d_ws, size_t ws_size,
                              hipStream_t stream) {
  const float* f = (const float*)d_in[0];  // (B,N,C) fp32
  const float* W = (const float*)d_in[1];  // (K,C)  fp32
  float* out = (float*)d_out;

  const long MBy = 1l << 20;
  char* ws = (char*)d_ws;
  short* hb = (short*)ws;                              // 32 MB (h / bf16 partials)
  short* fbf = (short*)(ws + 32 * MBy);                // 32 MB
  short* fhbf = (short*)(ws + 64 * MBy);               // 32 MB
  unsigned char* zq = (unsigned char*)(ws + 96 * MBy); // 16 MB
  unsigned char* WnA = (unsigned char*)(ws + 112 * MBy);  // 2 MB
  unsigned char* WtB = (unsigned char*)(ws + 114 * MBy);  // 2 MB
  float* zpart = (float*)(ws + 116 * MBy);             // 4 MB region (uses 2)
  float* wsqf = (float*)(ws + 120 * MBy);              // 16 KB
  float* csum = (float*)(ws + 120 * MBy + (1l << 16)); // 64 KB
  float* lpart = (float*)(ws + 120 * MBy + (1l << 17)); // 128 KB
  double* accum = (double*)(ws + 121 * MBy);           // 2 KB

  hipMemsetAsync(accum, 0, 256 * sizeof(double), stream);

  wsq_kernel<<<K, 256, 0, stream>>>(W, wsqf);
  colsum_kernel<<<NCH, 256, 0, stream>>>(W, csum);
  prep_w<<<K / 32, 256, 0, stream>>>(W, WnA, WtB);
  init_f<<<B * 32, 256, 0, stream>>>(f, fbf, zpart);
  reduce_zpart<<<(B * 128 + 255) / 256, 256, 0, stream>>>(zpart, zq, 1);

  for (int s = 0; s < SN; ++s) {
    int pn = 1 << s;
    int M = B * pn;
    int gx = (M + 63) / 64;
    int KS = 512 / gx;
    if (KS < 1) KS = 1;
    if (KS > 32) KS = 32;
    flash_mfma<<<dim3(gx, KS), 256, 0, stream>>>(zq, WnA, WtB, wsqf, csum, hb, lpart, M, KS);
    if (KS > 1)
      combine_kernel<<<(int)(((long)M * 128 + 255) / 256), 256, 0, stream>>>(hb, lpart, M, KS);
    int pn_next = (s < SN - 1) ? (pn << 1) : 0;
    fused_up<<<B * 32, 256, 0, stream>>>(hb, fbf, fhbf, fhbf, out, zq, zpart, accum,
                                         pn, pn_next, s == 0 ? 1 : 0, s == SN - 1 ? 1 : 0);
    if (pn_next && pn_next < 64)
      reduce_zpart<<<(int)(((long)B * pn_next * 128 + 255) / 256), 256, 0, stream>>>(zpart, zq, pn_next);
  }

  finalize_kernel<<<1, 64, 0, stream>>>(accum, out + BCN);
}

// Round 9
// 951.914 us; speedup vs baseline: 2.6113x; 1.0804x over previous
//
#include <hip/hip_runtime.h>
#include <hip/hip_bf16.h>

constexpr int B = 32, N = 1024, C = 512, K = 4096, SN = 11;
constexpr long BCN = (long)B * N * C;  // 16,777,216
constexpr int TKC = 128;               // keys per flash chunk
constexpr int NCH = K / TKC;           // 32 chunks
constexpr float PSCALE = 256.f;        // p' = PSCALE*(p-1) stored in fp8
constexpr int SCONE = 0x7f7f7f7f;      // e8m0 scale 1.0 in every byte

typedef __attribute__((ext_vector_type(4))) float f32x4;
typedef __attribute__((ext_vector_type(16))) float f32x16;
typedef __attribute__((ext_vector_type(8))) int i32x8;
typedef __attribute__((ext_vector_type(4))) int i32x4;
typedef unsigned int u32;
typedef unsigned long u64;

static __device__ __forceinline__ short f2bf(float x) {
  __hip_bfloat16 h = __float2bfloat16(x);
  short s;
  __builtin_memcpy(&s, &h, sizeof(s));
  return s;
}
static __device__ __forceinline__ float bf2f(short s) {
  u32 u = ((u32)(unsigned short)s) << 16;
  float f;
  __builtin_memcpy(&f, &u, 4);
  return f;
}
static __device__ __forceinline__ u32 pk4_fp8(float a, float b, float c, float d) {
  int r = __builtin_amdgcn_cvt_pk_fp8_f32(a, b, 0, false);
  r = __builtin_amdgcn_cvt_pk_fp8_f32(c, d, r, true);
  return (u32)r;
}
static __device__ __forceinline__ f32x16 zero16() {
  f32x16 z;
#pragma unroll
  for (int i = 0; i < 16; ++i) z[i] = 0.f;
  return z;
}

// ---------------------------------------------------------------------------
// w_sq[k] = sum_c W[k,c]^2  (fp32 W — enters d exactly)
__global__ __launch_bounds__(256) void wsq_kernel(const float* __restrict__ W,
                                                  float* __restrict__ wsq) {
  __shared__ float red[256];
  int k = blockIdx.x;
  const float* row = W + (long)k * C;
  float s = 0.f;
  for (int c = threadIdx.x; c < C; c += 256) {
    float v = row[c];
    s += v * v;
  }
  red[threadIdx.x] = s;
  __syncthreads();
  for (int off = 128; off > 0; off >>= 1) {
    if (threadIdx.x < off) red[threadIdx.x] += red[threadIdx.x + off];
    __syncthreads();
  }
  if (threadIdx.x == 0) wsq[k] = red[0];
}

// csum[ch][c] = sum over the chunk's 128 keys of W[k][c] (fp32, for the p' trick)
__global__ __launch_bounds__(256) void colsum_kernel(const float* __restrict__ W,
                                                     float* __restrict__ csum) {
  int ch = blockIdx.x;
  const float* base = W + (long)ch * TKC * C;
  float s0 = 0.f, s1 = 0.f;
  for (int k = 0; k < TKC; ++k) {
    s0 += base[(long)k * C + threadIdx.x];
    s1 += base[(long)k * C + threadIdx.x + 256];
  }
  csum[ch * C + threadIdx.x] = s0;
  csum[ch * C + threadIdx.x + 256] = s1;
}

// ---------------------------------------------------------------------------
// fp8 fragment-packed W for mfma_scale_f32_32x32x64_f8f6f4 (2KB lane-linear
// units = unit*2048 + lane*32 bytes):
//  WnA (phase-1 A / keys x C):  unit u = t*8+cc  : lane L byte j holds
//     W[t*32+(L&31)][cc*64+(L>>5)*32+j]            (t = key32 block 0..127)
//  WtB (phase-2 B / keys x C):  unit u = f2*16+c2: lane L byte j holds
//     W[f2*64+(L>>5)*32+j][c2*32+(L&31)]           (f2 = key64 block 0..63)
// One block per 32 keys; 128 blocks.
__global__ __launch_bounds__(256) void prep_w(const float* __restrict__ W,
                                              unsigned char* __restrict__ WnA,
                                              unsigned char* __restrict__ WtB) {
  __shared__ __attribute__((aligned(16))) unsigned char tile[32 * 520];  // [key][c]
  const int blk = blockIdx.x, tid = threadIdx.x;
  const float* src = W + (long)blk * 32 * C;
#pragma unroll
  for (int i = 0; i < 16; ++i) {
    int idx = tid + i * 256;  // 4096 float4 groups
    float4 v = ((const float4*)src)[idx];
    int key = idx >> 7, c = (idx & 127) * 4;
    *(u32*)&tile[key * 520 + c] = pk4_fp8(v.x, v.y, v.z, v.w);
  }
  __syncthreads();
  // WnA units for t = blk (8 units, 64 lanes each -> 512 slots of 32B)
#pragma unroll
  for (int i = 0; i < 2; ++i) {
    int slot = tid + i * 256;
    int cc = slot >> 6, L = slot & 63;
    const unsigned char* sp = &tile[(L & 31) * 520 + cc * 64 + (L >> 5) * 32];
    u64* dst = (u64*)(WnA + ((long)(blk * 8 + cc) * 64 + L) * 32);
    dst[0] = *(const u64*)(sp);
    dst[1] = *(const u64*)(sp + 8);
    dst[2] = *(const u64*)(sp + 16);
    dst[3] = *(const u64*)(sp + 24);
  }
  // WtB half-units: f2 = blk>>1, h = blk&1 provides lanes with (L>>5)==h
#pragma unroll
  for (int i = 0; i < 2; ++i) {
    int slot = tid + i * 256;  // c2 = slot>>5 (0..15), rho = slot&31
    int c2 = slot >> 5, rho = slot & 31;
    union { unsigned char v[32]; u64 q[4]; } t;
#pragma unroll
    for (int j = 0; j < 32; ++j) t.v[j] = tile[j * 520 + c2 * 32 + rho];
    u64* dst = (u64*)(WtB + ((long)((blk >> 1) * 16 + c2) * 64 + (blk & 1) * 32 + rho) * 32);
    dst[0] = t.q[0]; dst[1] = t.q[1]; dst[2] = t.q[2]; dst[3] = t.q[3];
  }
}

// ---------------------------------------------------------------------------
// f (fp32) -> fbf (bf16) + gran-16 partial sums for the pn=1 z.
__global__ __launch_bounds__(256) void init_f(const float* __restrict__ f,
                                              short* __restrict__ fbf,
                                              float* __restrict__ zpart) {
  int b = blockIdx.x >> 5;
  int n0 = (blockIdx.x & 31) * 32 + (threadIdx.x >> 7) * 16;
  int c4 = threadIdx.x & 127;
  float ax = 0, ay = 0, az = 0, aw = 0;
  for (int j = 0; j < 16; ++j) {
    long e = ((long)b * N + n0 + j) * 128 + c4;
    float4 v = ((const float4*)f)[e];
    short4 o = {f2bf(v.x), f2bf(v.y), f2bf(v.z), f2bf(v.w)};
    ((short4*)fbf)[e] = o;
    ax += v.x; ay += v.y; az += v.z; aw += v.w;
  }
  float4 zp = {ax, ay, az, aw};
  ((float4*)zpart)[((long)b * 64 + (n0 >> 4)) * 128 + c4] = zp;
}

// zpart (gran-16 sums, [B][64][C] fp32) -> z fp8 at pn<=32 rows (mean over bs).
__global__ __launch_bounds__(256) void reduce_zpart(const float* __restrict__ zpart,
                                                    unsigned char* __restrict__ zq, int pn) {
  long idx = (long)blockIdx.x * 256 + threadIdx.x;
  long tot = (long)B * pn * 128;
  if (idx >= tot) return;
  int c4 = (int)(idx & 127);
  long row = idx >> 7;
  int b = (int)(row / pn), j = (int)(row % pn);
  int r = 64 / pn;
  float ax = 0, ay = 0, az = 0, aw = 0;
  for (int i = 0; i < r; ++i) {
    float4 v = ((const float4*)zpart)[((long)b * 64 + j * r + i) * 128 + c4];
    ax += v.x; ay += v.y; az += v.z; aw += v.w;
  }
  float inv = (float)pn / (float)N;
  *(u32*)&zq[row * C + c4 * 4] = pk4_fp8(ax * inv, ay * inv, az * inv, aw * inv);
}

// ---------------------------------------------------------------------------
// fp8 MX-MFMA flash (32x32x64, unit scales), inverted dataflow, 1 barrier per
// chunk (double-buffered P). 64 z-rows per 256-thread/4-wave block — the
// measured-optimal configuration (142us @ pn=1024): 32-row doubles W-frag L2
// traffic per FLOP (-40%), 128-row spills registers (hacc 128 AGPR + working
// set > 256/wave). No setprio (measured negative here), no LDS swizzle
// (conflicts off critical path), full __syncthreads (vmcnt-preserving soft
// barrier measured neutral). p' = PSCALE*(exp(wsq-2s)-1) in fp8;
// H = sum(csum) + H'/PSCALE. K-split over grid.y sums linearly.
__global__ __launch_bounds__(256, 2) void flash_mfma(
    const unsigned char* __restrict__ zq, const unsigned char* __restrict__ WnA,
    const unsigned char* __restrict__ WtB, const float* __restrict__ wsq,
    const float* __restrict__ csum, short* __restrict__ hb,
    float* __restrict__ lpart, int M, int KS) {
  __shared__ __attribute__((aligned(16))) unsigned char ZS[16 * 2048];      // 32KB
  __shared__ __attribute__((aligned(16))) unsigned char PS[2][4 * 2048];    // 2x8KB
  const int tid = threadIdx.x;
  const int w = tid >> 6, lane = tid & 63;
  const int rho = lane & 31, hi = lane >> 5;
  const long row0 = (long)blockIdx.x * 64;
  const int nc = NCH / KS, ch0 = blockIdx.y * nc;

  // stage Z (fp8) into 32x32x64 B-frag units: unit u = zt*8+cc, lane L byte j
  // holds Z[row0+zt*32+(L&31)][cc*64+(L>>5)*32+j]  (zero-pad rows >= M)
#pragma unroll
  for (int i = 0; i < 4; ++i) {
    int u = i * 4 + w, zt = u >> 3, cc = u & 7;
    long row = row0 + zt * 32 + rho;
    u64 v0 = 0, v1 = 0, v2 = 0, v3 = 0;
    if (row < M) {
      const u64* sp = (const u64*)(zq + row * C + cc * 64 + hi * 32);
      v0 = sp[0]; v1 = sp[1]; v2 = sp[2]; v3 = sp[3];
    }
    u64* dp = (u64*)(ZS + u * 2048 + lane * 32);
    dp[0] = v0; dp[1] = v1; dp[2] = v2; dp[3] = v3;
  }
  f32x16 hacc[2][4];
#pragma unroll
  for (int zt = 0; zt < 2; ++zt)
#pragma unroll
    for (int ct = 0; ct < 4; ++ct) hacc[zt][ct] = zero16();
  float lreg[2] = {0.f, 0.f};
  float cs[4] = {0.f, 0.f, 0.f, 0.f};
  __syncthreads();

#pragma unroll 1
  for (int ci = 0; ci < nc; ++ci) {
    const int ch = ch0 + ci;
#pragma unroll
    for (int ct = 0; ct < 4; ++ct) cs[ct] += csum[ch * C + w * 128 + ct * 32 + rho];
    // phase 1: S^T(32 keys x 64 zrows) = W.Z^T ; keys = ch*128 + w*32 + [0,32)
    f32x16 s[2];
    s[0] = zero16();
    s[1] = zero16();
    const unsigned char* wa = WnA + ((long)(ch * 4 + w) * 8) * 2048 + lane * 32;
    const unsigned char* zb = ZS + lane * 32;
#pragma unroll
    for (int cc = 0; cc < 8; ++cc) {
      i32x8 a = *(const i32x8*)(wa + cc * 2048);
      i32x8 b0 = *(const i32x8*)(zb + cc * 2048);
      i32x8 b1 = *(const i32x8*)(zb + (8 + cc) * 2048);
      s[0] = __builtin_amdgcn_mfma_scale_f32_32x32x64_f8f6f4(a, b0, s[0], 0, 0, 0, SCONE, 0, SCONE);
      s[1] = __builtin_amdgcn_mfma_scale_f32_32x32x64_f8f6f4(a, b1, s[1], 0, 0, 0, SCONE, 0, SCONE);
    }
    // softmax weights: p'=PSCALE*(p-1) -> fp8 A-frags in PS[ci&1].
    // D mapping: key-in-wave kappa = (r&3)+8*(r>>2)+4*hi, zrow = rho.
    const float* wsb = wsq + ch * TKC + w * 32 + hi * 4;
    float wv[16];
#pragma unroll
    for (int g = 0; g < 4; ++g) {
      float4 t = *(const float4*)(wsb + 8 * g);
      wv[4 * g + 0] = t.x; wv[4 * g + 1] = t.y; wv[4 * g + 2] = t.z; wv[4 * g + 3] = t.w;
    }
    unsigned char* Pun = PS[ci & 1] + (w >> 1) * 2048;
    const int pbase = (w & 1) * 1024 + rho * 32 + hi * 4;
#pragma unroll
    for (int zt = 0; zt < 2; ++zt) {
      float sum = 0.f, pv[16];
#pragma unroll
      for (int r = 0; r < 16; ++r) {
        float e = __expf(wv[r] - 2.f * s[zt][r]);
        sum += e;
        pv[r] = PSCALE * e - PSCALE;
      }
      lreg[zt] += sum;
#pragma unroll
      for (int g = 0; g < 4; ++g) {
        u32 pk = pk4_fp8(pv[4 * g], pv[4 * g + 1], pv[4 * g + 2], pv[4 * g + 3]);
        *(u32*)(Pun + zt * 4096 + pbase + 8 * g) = pk;
      }
    }
    __syncthreads();  // single barrier per chunk (P double-buffered)
    // phase 2: H'(64 x 128c-slice) += P'.W ; W B-frags from L2
#pragma unroll
    for (int kc = 0; kc < 2; ++kc) {
      const unsigned char* Pr = PS[ci & 1] + lane * 32;
      i32x8 pa[2];
      pa[0] = *(const i32x8*)(Pr + (0 * 2 + kc) * 2048);
      pa[1] = *(const i32x8*)(Pr + (1 * 2 + kc) * 2048);
      const unsigned char* wb = WtB + ((long)(ch * 2) * 16 + w * 4) * 2048 + lane * 32;
#pragma unroll
      for (int ct = 0; ct < 4; ++ct) {
        i32x8 bw = *(const i32x8*)(wb + (kc * 16 + ct) * 2048);
        hacc[0][ct] = __builtin_amdgcn_mfma_scale_f32_32x32x64_f8f6f4(pa[0], bw, hacc[0][ct], 0, 0, 0, SCONE, 0, SCONE);
        hacc[1][ct] = __builtin_amdgcn_mfma_scale_f32_32x32x64_f8f6f4(pa[1], bw, hacc[1][ct], 0, 0, 0, SCONE, 0, SCONE);
      }
    }
  }
  // cross-wave l reduction
  __syncthreads();
  lreg[0] += __shfl_xor(lreg[0], 32);
  lreg[1] += __shfl_xor(lreg[1], 32);
  float* l4 = (float*)PS;  // [64][4]
  if (hi == 0) {
    l4[rho * 4 + w] = lreg[0];
    l4[(32 + rho) * 4 + w] = lreg[1];
  }
  __syncthreads();
  constexpr float PINV = 1.f / PSCALE;
  if (KS == 1) {
#pragma unroll
    for (int zt = 0; zt < 2; ++zt)
#pragma unroll
      for (int r = 0; r < 16; ++r) {
        int rr = zt * 32 + (r & 3) + 8 * (r >> 2) + 4 * hi;
        long row = row0 + rr;
        if (row < M) {
          float4 lv = ((const float4*)l4)[rr];
          float inv = 1.f / (lv.x + lv.y + lv.z + lv.w);
#pragma unroll
          for (int ct = 0; ct < 4; ++ct)
            hb[row * C + (w * 4 + ct) * 32 + rho] =
                f2bf((cs[ct] + hacc[zt][ct][r] * PINV) * inv);
        }
      }
  } else {
    long base = (long)blockIdx.y * M * C;
#pragma unroll
    for (int zt = 0; zt < 2; ++zt)
#pragma unroll
      for (int r = 0; r < 16; ++r) {
        int rr = zt * 32 + (r & 3) + 8 * (r >> 2) + 4 * hi;
        long row = row0 + rr;
        if (row < M) {
#pragma unroll
          for (int ct = 0; ct < 4; ++ct)
            hb[base + row * C + (w * 4 + ct) * 32 + rho] =
                f2bf(cs[ct] + hacc[zt][ct][r] * PINV);
        }
      }
    if (w == 0) {
      long row = row0 + lane;
      if (row < M) {
        float4 lv = ((const float4*)l4)[lane];
        lpart[(long)blockIdx.y * M + row] = lv.x + lv.y + lv.z + lv.w;
      }
    }
  }
}

// ---------------------------------------------------------------------------
// In-place: hb[m][c] = (sum_s hpart[s][m][c]) / (sum_s lpart[s][m]).
__global__ __launch_bounds__(256) void combine_kernel(short* __restrict__ hb,
                                                      const float* __restrict__ lpart,
                                                      int M, int KS) {
  long idx = (long)blockIdx.x * 256 + threadIdx.x;
  long tot = (long)M * 128;  // short4 groups
  if (idx >= tot) return;
  int m = (int)(idx >> 7);
  float lsum = 0.f;
  for (int s = 0; s < KS; ++s) lsum += lpart[(long)s * M + m];
  float ax = 0, ay = 0, az = 0, aw = 0;
  for (int s = 0; s < KS; ++s) {
    short4 v = ((const short4*)hb)[(long)s * tot + idx];
    ax += bf2f(v.x); ay += bf2f(v.y); az += bf2f(v.z); aw += bf2f(v.w);
  }
  float inv = 1.f / lsum;
  short4 o = {f2bf(ax * inv), f2bf(ay * inv), f2bf(az * inv), f2bf(aw * inv)};
  ((short4*)hb)[idx] = o;
}

// ---------------------------------------------------------------------------
// Fused: fhat += upsample(h); loss; emit next-scale z (fp8 direct if
// pn_next>=64, else gran-16 fp32 partials). Last scale writes fp32 d_out.
__global__ __launch_bounds__(256) void fused_up(
    const short* __restrict__ hb, const short* __restrict__ fbf,
    const short* fhin, short* fhout, float* __restrict__ outf,
    unsigned char* __restrict__ zq, float* __restrict__ zpart,
    double* __restrict__ accum, int pn, int pn_next, int first, int last) {
  const int b = blockIdx.x >> 5;
  const int n0 = (blockIdx.x & 31) * 32 + (threadIdx.x >> 7) * 16;
  const int c4 = threadIdx.x & 127;
  const float scale = (float)pn * (1.f / (float)N);
  const int bs_next = pn_next ? (N / pn_next) : 0;
  float zx = 0, zy = 0, zz = 0, zw = 0, part = 0.f;
  for (int j = 0; j < 16; ++j) {
    int n = n0 + j;
    long e = ((long)b * N + n) * 128 + c4;
    float coords = ((float)n + 0.5f) * scale - 0.5f;
    coords = fminf(fmaxf(coords, 0.f), (float)(pn - 1));
    int i0 = (int)coords;
    int i1 = min(i0 + 1, pn - 1);
    float wq = coords - (float)i0, ow = 1.f - wq;
    short4 h0 = ((const short4*)hb)[((long)b * pn + i0) * 128 + c4];
    short4 h1 = ((const short4*)hb)[((long)b * pn + i1) * 128 + c4];
    short4 fv = ((const short4*)fbf)[e];
    float fhx, fhy, fhz, fhw;
    if (first) {
      fhx = fhy = fhz = fhw = 0.f;
    } else {
      short4 p = ((const short4*)fhin)[e];
      fhx = bf2f(p.x); fhy = bf2f(p.y); fhz = bf2f(p.z); fhw = bf2f(p.w);
    }
    fhx += bf2f(h0.x) * ow + bf2f(h1.x) * wq;
    fhy += bf2f(h0.y) * ow + bf2f(h1.y) * wq;
    fhz += bf2f(h0.z) * ow + bf2f(h1.z) * wq;
    fhw += bf2f(h0.w) * ow + bf2f(h1.w) * wq;
    if (last) {
      float4 o = {fhx, fhy, fhz, fhw};
      ((float4*)outf)[e] = o;
    } else {
      short4 o = {f2bf(fhx), f2bf(fhy), f2bf(fhz), f2bf(fhw)};
      ((short4*)fhout)[e] = o;
    }
    float dx = fhx - bf2f(fv.x), dy = fhy - bf2f(fv.y);
    float dz = fhz - bf2f(fv.z), dw = fhw - bf2f(fv.w);
    part += dx * dx + dy * dy + dz * dz + dw * dw;
    zx -= dx; zy -= dy; zz -= dz; zw -= dw;
    if (pn_next >= 64) {
      if (((n + 1) & (bs_next - 1)) == 0) {
        float inv = 1.f / (float)bs_next;
        *(u32*)&zq[((long)b * pn_next + n / bs_next) * C + c4 * 4] =
            pk4_fp8(zx * inv, zy * inv, zz * inv, zw * inv);
        zx = zy = zz = zw = 0.f;
      }
    }
  }
  if (pn_next && pn_next < 64) {
    float4 zp = {zx, zy, zz, zw};
    ((float4*)zpart)[((long)b * 64 + (n0 >> 4)) * 128 + c4] = zp;
  }
  __shared__ float red[256];
  red[threadIdx.x] = part;
  __syncthreads();
  for (int off = 128; off > 0; off >>= 1) {
    if (threadIdx.x < off) red[threadIdx.x] += red[threadIdx.x + off];
    __syncthreads();
  }
  if (threadIdx.x == 0) atomicAdd(&accum[blockIdx.x & 255], (double)red[0]);
}

// ---------------------------------------------------------------------------
__global__ void finalize_kernel(const double* __restrict__ accum,
                                float* __restrict__ out_scalars) {
  if (threadIdx.x == 0 && blockIdx.x == 0) {
    double s = 0.0;
    for (int i = 0; i < 256; ++i) s += accum[i];
    double denom = (double)SN * (double)BCN;
    out_scalars[0] = (float)(0.25 * s / denom);  // commit
    out_scalars[1] = (float)(s / denom);         // qlat
  }
}

// ---------------------------------------------------------------------------
extern "C" void kernel_launch(void* const* d_in, const int* in_sizes, int n_in,
                              void* d_out, int out_size, void* d_ws, size_t ws_size,
                              hipStream_t stream) {
  const float* f = (const float*)d_in[0];  // (B,N,C) fp32
  const float* W = (const float*)d_in[1];  // (K,C)  fp32
  float* out = (float*)d_out;

  const long MBy = 1l << 20;
  char* ws = (char*)d_ws;
  short* hb = (short*)ws;                              // 32 MB (h / bf16 partials)
  short* fbf = (short*)(ws + 32 * MBy);                // 32 MB
  short* fhbf = (short*)(ws + 64 * MBy);               // 32 MB
  unsigned char* zq = (unsigned char*)(ws + 96 * MBy); // 16 MB
  unsigned char* WnA = (unsigned char*)(ws + 112 * MBy);  // 2 MB
  unsigned char* WtB = (unsigned char*)(ws + 114 * MBy);  // 2 MB
  float* zpart = (float*)(ws + 116 * MBy);             // 4 MB region (uses 2)
  float* wsqf = (float*)(ws + 120 * MBy);              // 16 KB
  float* csum = (float*)(ws + 120 * MBy + (1l << 16)); // 64 KB
  float* lpart = (float*)(ws + 120 * MBy + (1l << 17)); // 128 KB
  double* accum = (double*)(ws + 121 * MBy);           // 2 KB

  hipMemsetAsync(accum, 0, 256 * sizeof(double), stream);

  wsq_kernel<<<K, 256, 0, stream>>>(W, wsqf);
  colsum_kernel<<<NCH, 256, 0, stream>>>(W, csum);
  prep_w<<<K / 32, 256, 0, stream>>>(W, WnA, WtB);
  init_f<<<B * 32, 256, 0, stream>>>(f, fbf, zpart);
  reduce_zpart<<<(B * 128 + 255) / 256, 256, 0, stream>>>(zpart, zq, 1);

  for (int s = 0; s < SN; ++s) {
    int pn = 1 << s;
    int M = B * pn;
    int gx = (M + 63) / 64;
    int KS = 512 / gx;
    if (KS < 1) KS = 1;
    if (KS > 32) KS = 32;
    flash_mfma<<<dim3(gx, KS), 256, 0, stream>>>(zq, WnA, WtB, wsqf, csum, hb, lpart, M, KS);
    if (KS > 1)
      combine_kernel<<<(int)(((long)M * 128 + 255) / 256), 256, 0, stream>>>(hb, lpart, M, KS);
    int pn_next = (s < SN - 1) ? (pn << 1) : 0;
    fused_up<<<B * 32, 256, 0, stream>>>(hb, fbf, fhbf, fhbf, out, zq, zpart, accum,
                                         pn, pn_next, s == 0 ? 1 : 0, s == SN - 1 ? 1 : 0);
    if (pn_next && pn_next < 64)
      reduce_zpart<<<(int)(((long)B * pn_next * 128 + 255) / 256), 256, 0, stream>>>(zpart, zq, pn_next);
  }

  finalize_kernel<<<1, 64, 0, stream>>>(accum, out + BCN);
}

// Round 10
// 919.386 us; speedup vs baseline: 2.7037x; 1.0354x over previous
//
#include <hip/hip_runtime.h>
#include <hip/hip_bf16.h>

constexpr int B = 32, N = 1024, C = 512, K = 4096, SN = 11;
constexpr long BCN = (long)B * N * C;  // 16,777,216
constexpr int TKC = 128;               // keys per flash chunk
constexpr int NCH = K / TKC;           // 32 chunks
constexpr float PSCALE = 256.f;        // p' = PSCALE*(p-1) stored in fp8
constexpr int SCONE = 0x7f7f7f7f;      // e8m0 scale 1.0 in every byte
constexpr float LOG2E = 1.4426950408889634f;

typedef __attribute__((ext_vector_type(4))) float f32x4;
typedef __attribute__((ext_vector_type(16))) float f32x16;
typedef __attribute__((ext_vector_type(8))) int i32x8;
typedef __attribute__((ext_vector_type(4))) int i32x4;
typedef unsigned int u32;
typedef unsigned long u64;

static __device__ __forceinline__ short f2bf(float x) {
  __hip_bfloat16 h = __float2bfloat16(x);
  short s;
  __builtin_memcpy(&s, &h, sizeof(s));
  return s;
}
static __device__ __forceinline__ float bf2f(short s) {
  u32 u = ((u32)(unsigned short)s) << 16;
  float f;
  __builtin_memcpy(&f, &u, 4);
  return f;
}
static __device__ __forceinline__ u32 pk4_fp8(float a, float b, float c, float d) {
  int r = __builtin_amdgcn_cvt_pk_fp8_f32(a, b, 0, false);
  r = __builtin_amdgcn_cvt_pk_fp8_f32(c, d, r, true);
  return (u32)r;
}
static __device__ __forceinline__ f32x16 zero16() {
  f32x16 z;
#pragma unroll
  for (int i = 0; i < 16; ++i) z[i] = 0.f;
  return z;
}

// ---------------------------------------------------------------------------
// wsq'[k] = (sum_c W[k,c]^2)*log2(e) + 8  — pre-scaled so flash's softmax is
// exp2-direct: e8 = 2^8*exp(wsq-2s) = exp2(wsq' - 2*log2e*s); p' = e8 - 256.
__global__ __launch_bounds__(256) void wsq_kernel(const float* __restrict__ W,
                                                  float* __restrict__ wsq) {
  __shared__ float red[256];
  int k = blockIdx.x;
  const float* row = W + (long)k * C;
  float s = 0.f;
  for (int c = threadIdx.x; c < C; c += 256) {
    float v = row[c];
    s += v * v;
  }
  red[threadIdx.x] = s;
  __syncthreads();
  for (int off = 128; off > 0; off >>= 1) {
    if (threadIdx.x < off) red[threadIdx.x] += red[threadIdx.x + off];
    __syncthreads();
  }
  if (threadIdx.x == 0) wsq[k] = red[0] * LOG2E + 8.0f;
}

// csum[ch][c] = sum over the chunk's 128 keys of W[k][c] (fp32, for the p' trick)
__global__ __launch_bounds__(256) void colsum_kernel(const float* __restrict__ W,
                                                     float* __restrict__ csum) {
  int ch = blockIdx.x;
  const float* base = W + (long)ch * TKC * C;
  float s0 = 0.f, s1 = 0.f;
  for (int k = 0; k < TKC; ++k) {
    s0 += base[(long)k * C + threadIdx.x];
    s1 += base[(long)k * C + threadIdx.x + 256];
  }
  csum[ch * C + threadIdx.x] = s0;
  csum[ch * C + threadIdx.x + 256] = s1;
}

// ---------------------------------------------------------------------------
// fp8 fragment-packed W for mfma_scale_f32_32x32x64_f8f6f4 (2KB lane-linear
// units = unit*2048 + lane*32 bytes):
//  WnA (phase-1 A / keys x C):  unit u = t*8+cc  : lane L byte j holds
//     W[t*32+(L&31)][cc*64+(L>>5)*32+j]            (t = key32 block 0..127)
//  WtB (phase-2 B / keys x C):  unit u = f2*16+c2: lane L byte j holds
//     W[f2*64+(L>>5)*32+j][c2*32+(L&31)]           (f2 = key64 block 0..63)
// One block per 32 keys; 128 blocks.
__global__ __launch_bounds__(256) void prep_w(const float* __restrict__ W,
                                              unsigned char* __restrict__ WnA,
                                              unsigned char* __restrict__ WtB) {
  __shared__ __attribute__((aligned(16))) unsigned char tile[32 * 520];  // [key][c]
  const int blk = blockIdx.x, tid = threadIdx.x;
  const float* src = W + (long)blk * 32 * C;
#pragma unroll
  for (int i = 0; i < 16; ++i) {
    int idx = tid + i * 256;  // 4096 float4 groups
    float4 v = ((const float4*)src)[idx];
    int key = idx >> 7, c = (idx & 127) * 4;
    *(u32*)&tile[key * 520 + c] = pk4_fp8(v.x, v.y, v.z, v.w);
  }
  __syncthreads();
  // WnA units for t = blk (8 units, 64 lanes each -> 512 slots of 32B)
#pragma unroll
  for (int i = 0; i < 2; ++i) {
    int slot = tid + i * 256;
    int cc = slot >> 6, L = slot & 63;
    const unsigned char* sp = &tile[(L & 31) * 520 + cc * 64 + (L >> 5) * 32];
    u64* dst = (u64*)(WnA + ((long)(blk * 8 + cc) * 64 + L) * 32);
    dst[0] = *(const u64*)(sp);
    dst[1] = *(const u64*)(sp + 8);
    dst[2] = *(const u64*)(sp + 16);
    dst[3] = *(const u64*)(sp + 24);
  }
  // WtB half-units: f2 = blk>>1, h = blk&1 provides lanes with (L>>5)==h
#pragma unroll
  for (int i = 0; i < 2; ++i) {
    int slot = tid + i * 256;  // c2 = slot>>5 (0..15), rho = slot&31
    int c2 = slot >> 5, rho = slot & 31;
    union { unsigned char v[32]; u64 q[4]; } t;
#pragma unroll
    for (int j = 0; j < 32; ++j) t.v[j] = tile[j * 520 + c2 * 32 + rho];
    u64* dst = (u64*)(WtB + ((long)((blk >> 1) * 16 + c2) * 64 + (blk & 1) * 32 + rho) * 32);
    dst[0] = t.q[0]; dst[1] = t.q[1]; dst[2] = t.q[2]; dst[3] = t.q[3];
  }
}

// ---------------------------------------------------------------------------
// f (fp32) -> fbf (bf16) + gran-16 partial sums for the pn=1 z.
__global__ __launch_bounds__(256) void init_f(const float* __restrict__ f,
                                              short* __restrict__ fbf,
                                              float* __restrict__ zpart) {
  int b = blockIdx.x >> 5;
  int n0 = (blockIdx.x & 31) * 32 + (threadIdx.x >> 7) * 16;
  int c4 = threadIdx.x & 127;
  float ax = 0, ay = 0, az = 0, aw = 0;
  for (int j = 0; j < 16; ++j) {
    long e = ((long)b * N + n0 + j) * 128 + c4;
    float4 v = ((const float4*)f)[e];
    short4 o = {f2bf(v.x), f2bf(v.y), f2bf(v.z), f2bf(v.w)};
    ((short4*)fbf)[e] = o;
    ax += v.x; ay += v.y; az += v.z; aw += v.w;
  }
  float4 zp = {ax, ay, az, aw};
  ((float4*)zpart)[((long)b * 64 + (n0 >> 4)) * 128 + c4] = zp;
}

// zpart (gran-16 sums, [B][64][C] fp32) -> z fp8 at pn<=32 rows (mean over bs).
__global__ __launch_bounds__(256) void reduce_zpart(const float* __restrict__ zpart,
                                                    unsigned char* __restrict__ zq, int pn) {
  long idx = (long)blockIdx.x * 256 + threadIdx.x;
  long tot = (long)B * pn * 128;
  if (idx >= tot) return;
  int c4 = (int)(idx & 127);
  long row = idx >> 7;
  int b = (int)(row / pn), j = (int)(row % pn);
  int r = 64 / pn;
  float ax = 0, ay = 0, az = 0, aw = 0;
  for (int i = 0; i < r; ++i) {
    float4 v = ((const float4*)zpart)[((long)b * 64 + j * r + i) * 128 + c4];
    ax += v.x; ay += v.y; az += v.z; aw += v.w;
  }
  float inv = (float)pn / (float)N;
  *(u32*)&zq[row * C + c4 * 4] = pk4_fp8(ax * inv, ay * inv, az * inv, aw * inv);
}

// ---------------------------------------------------------------------------
// fp8 MX-MFMA flash (32x32x64, unit scales), inverted dataflow, 1 barrier per
// chunk (double-buffered P). 64 z-rows per 256-thread/4-wave block — the
// measured-optimal configuration (142us @ pn=1024): 32-row doubles W-frag L2
// traffic per FLOP (-40%), 128-row spills registers. No setprio (measured
// negative), no LDS swizzle (conflicts off critical path), full __syncthreads
// (soft barrier measured neutral). Softmax is exp2-direct: wsq pre-scaled to
// wsq*log2e+8, so e8 = exp2(fma(s,-2log2e,wsq')) = 256*exp(wsq-2s);
// p' = e8 - 256 (1 fewer VALU op/exp); lreg scaled by 2^-8 once per wave.
// H = sum(csum) + H'/PSCALE. K-split over grid.y sums linearly.
__global__ __launch_bounds__(256, 2) void flash_mfma(
    const unsigned char* __restrict__ zq, const unsigned char* __restrict__ WnA,
    const unsigned char* __restrict__ WtB, const float* __restrict__ wsq,
    const float* __restrict__ csum, short* __restrict__ hb,
    float* __restrict__ lpart, int M, int KS) {
  __shared__ __attribute__((aligned(16))) unsigned char ZS[16 * 2048];      // 32KB
  __shared__ __attribute__((aligned(16))) unsigned char PS[2][4 * 2048];    // 2x8KB
  const int tid = threadIdx.x;
  const int w = tid >> 6, lane = tid & 63;
  const int rho = lane & 31, hi = lane >> 5;
  const long row0 = (long)blockIdx.x * 64;
  const int nc = NCH / KS, ch0 = blockIdx.y * nc;
  constexpr float NL2E = -2.f * LOG2E;

  // stage Z (fp8) into 32x32x64 B-frag units: unit u = zt*8+cc, lane L byte j
  // holds Z[row0+zt*32+(L&31)][cc*64+(L>>5)*32+j]  (zero-pad rows >= M)
#pragma unroll
  for (int i = 0; i < 4; ++i) {
    int u = i * 4 + w, zt = u >> 3, cc = u & 7;
    long row = row0 + zt * 32 + rho;
    u64 v0 = 0, v1 = 0, v2 = 0, v3 = 0;
    if (row < M) {
      const u64* sp = (const u64*)(zq + row * C + cc * 64 + hi * 32);
      v0 = sp[0]; v1 = sp[1]; v2 = sp[2]; v3 = sp[3];
    }
    u64* dp = (u64*)(ZS + u * 2048 + lane * 32);
    dp[0] = v0; dp[1] = v1; dp[2] = v2; dp[3] = v3;
  }
  f32x16 hacc[2][4];
#pragma unroll
  for (int zt = 0; zt < 2; ++zt)
#pragma unroll
    for (int ct = 0; ct < 4; ++ct) hacc[zt][ct] = zero16();
  float lreg[2] = {0.f, 0.f};
  float cs[4] = {0.f, 0.f, 0.f, 0.f};
  __syncthreads();

#pragma unroll 1
  for (int ci = 0; ci < nc; ++ci) {
    const int ch = ch0 + ci;
#pragma unroll
    for (int ct = 0; ct < 4; ++ct) cs[ct] += csum[ch * C + w * 128 + ct * 32 + rho];
    // phase 1: S^T(32 keys x 64 zrows) = W.Z^T ; keys = ch*128 + w*32 + [0,32)
    f32x16 s[2];
    s[0] = zero16();
    s[1] = zero16();
    const unsigned char* wa = WnA + ((long)(ch * 4 + w) * 8) * 2048 + lane * 32;
    const unsigned char* zb = ZS + lane * 32;
#pragma unroll
    for (int cc = 0; cc < 8; ++cc) {
      i32x8 a = *(const i32x8*)(wa + cc * 2048);
      i32x8 b0 = *(const i32x8*)(zb + cc * 2048);
      i32x8 b1 = *(const i32x8*)(zb + (8 + cc) * 2048);
      s[0] = __builtin_amdgcn_mfma_scale_f32_32x32x64_f8f6f4(a, b0, s[0], 0, 0, 0, SCONE, 0, SCONE);
      s[1] = __builtin_amdgcn_mfma_scale_f32_32x32x64_f8f6f4(a, b1, s[1], 0, 0, 0, SCONE, 0, SCONE);
    }
    // softmax weights: p' = e8 - 256 -> fp8 A-frags in PS[ci&1].
    // D mapping: key-in-wave kappa = (r&3)+8*(r>>2)+4*hi, zrow = rho.
    const float* wsb = wsq + ch * TKC + w * 32 + hi * 4;
    float wv[16];
#pragma unroll
    for (int g = 0; g < 4; ++g) {
      float4 t = *(const float4*)(wsb + 8 * g);
      wv[4 * g + 0] = t.x; wv[4 * g + 1] = t.y; wv[4 * g + 2] = t.z; wv[4 * g + 3] = t.w;
    }
    unsigned char* Pun = PS[ci & 1] + (w >> 1) * 2048;
    const int pbase = (w & 1) * 1024 + rho * 32 + hi * 4;
#pragma unroll
    for (int zt = 0; zt < 2; ++zt) {
      float sum = 0.f, pv[16];
#pragma unroll
      for (int r = 0; r < 16; ++r) {
        float e8 = __builtin_amdgcn_exp2f(fmaf(s[zt][r], NL2E, wv[r]));
        sum += e8;
        pv[r] = e8 - PSCALE;
      }
      lreg[zt] += sum;
#pragma unroll
      for (int g = 0; g < 4; ++g) {
        u32 pk = pk4_fp8(pv[4 * g], pv[4 * g + 1], pv[4 * g + 2], pv[4 * g + 3]);
        *(u32*)(Pun + zt * 4096 + pbase + 8 * g) = pk;
      }
    }
    __syncthreads();  // single barrier per chunk (P double-buffered)
    // phase 2: H'(64 x 128c-slice) += P'.W ; W B-frags from L2
#pragma unroll
    for (int kc = 0; kc < 2; ++kc) {
      const unsigned char* Pr = PS[ci & 1] + lane * 32;
      i32x8 pa[2];
      pa[0] = *(const i32x8*)(Pr + (0 * 2 + kc) * 2048);
      pa[1] = *(const i32x8*)(Pr + (1 * 2 + kc) * 2048);
      const unsigned char* wb = WtB + ((long)(ch * 2) * 16 + w * 4) * 2048 + lane * 32;
#pragma unroll
      for (int ct = 0; ct < 4; ++ct) {
        i32x8 bw = *(const i32x8*)(wb + (kc * 16 + ct) * 2048);
        hacc[0][ct] = __builtin_amdgcn_mfma_scale_f32_32x32x64_f8f6f4(pa[0], bw, hacc[0][ct], 0, 0, 0, SCONE, 0, SCONE);
        hacc[1][ct] = __builtin_amdgcn_mfma_scale_f32_32x32x64_f8f6f4(pa[1], bw, hacc[1][ct], 0, 0, 0, SCONE, 0, SCONE);
      }
    }
  }
  // cross-wave l reduction (undo the 2^8 exp scaling once per wave)
  __syncthreads();
  lreg[0] += __shfl_xor(lreg[0], 32);
  lreg[1] += __shfl_xor(lreg[1], 32);
  lreg[0] *= 0.00390625f;
  lreg[1] *= 0.00390625f;
  float* l4 = (float*)PS;  // [64][4]
  if (hi == 0) {
    l4[rho * 4 + w] = lreg[0];
    l4[(32 + rho) * 4 + w] = lreg[1];
  }
  __syncthreads();
  constexpr float PINV = 1.f / PSCALE;
  if (KS == 1) {
#pragma unroll
    for (int zt = 0; zt < 2; ++zt)
#pragma unroll
      for (int r = 0; r < 16; ++r) {
        int rr = zt * 32 + (r & 3) + 8 * (r >> 2) + 4 * hi;
        long row = row0 + rr;
        if (row < M) {
          float4 lv = ((const float4*)l4)[rr];
          float inv = 1.f / (lv.x + lv.y + lv.z + lv.w);
#pragma unroll
          for (int ct = 0; ct < 4; ++ct)
            hb[row * C + (w * 4 + ct) * 32 + rho] =
                f2bf((cs[ct] + hacc[zt][ct][r] * PINV) * inv);
        }
      }
  } else {
    long base = (long)blockIdx.y * M * C;
#pragma unroll
    for (int zt = 0; zt < 2; ++zt)
#pragma unroll
      for (int r = 0; r < 16; ++r) {
        int rr = zt * 32 + (r & 3) + 8 * (r >> 2) + 4 * hi;
        long row = row0 + rr;
        if (row < M) {
#pragma unroll
          for (int ct = 0; ct < 4; ++ct)
            hb[base + row * C + (w * 4 + ct) * 32 + rho] =
                f2bf(cs[ct] + hacc[zt][ct][r] * PINV);
        }
      }
    if (w == 0) {
      long row = row0 + lane;
      if (row < M) {
        float4 lv = ((const float4*)l4)[lane];
        lpart[(long)blockIdx.y * M + row] = lv.x + lv.y + lv.z + lv.w;
      }
    }
  }
}

// ---------------------------------------------------------------------------
// Fused: fhat += upsample(h); loss; emit next-scale z (fp8 direct if
// pn_next>=64, else gran-16 fp32 partials). Last scale writes fp32 d_out.
// When KS>1, the K-split partials in hb are combined on the fly (read KS
// copies + lpart, normalize) — replaces the separate combine_kernel, saving
// one M*C bf16 write+read round-trip and a dispatch per scale.
__global__ __launch_bounds__(256) void fused_up(
    const short* __restrict__ hb, const float* __restrict__ lpart,
    const short* __restrict__ fbf, const short* fhin, short* fhout,
    float* __restrict__ outf, unsigned char* __restrict__ zq,
    float* __restrict__ zpart, double* __restrict__ accum,
    int pn, int pn_next, int KS, int first, int last) {
  const int b = blockIdx.x >> 5;
  const int n0 = (blockIdx.x & 31) * 32 + (threadIdx.x >> 7) * 16;
  const int c4 = threadIdx.x & 127;
  const int M = B * pn;
  const float scale = (float)pn * (1.f / (float)N);
  const int bs_next = pn_next ? (N / pn_next) : 0;
  float zx = 0, zy = 0, zz = 0, zw = 0, part = 0.f;
  // cached combined h rows (KS>1 path); rows advance monotonically with n
  int cache_i0 = -1, cache_i1 = -1;
  float4 ch0 = {0, 0, 0, 0}, ch1 = {0, 0, 0, 0};
  auto comb = [&](int row) -> float4 {
    long m = (long)b * pn + row;
    float ls = 0.f, ax = 0.f, ay = 0.f, az = 0.f, aw = 0.f;
    for (int s2 = 0; s2 < KS; ++s2) {
      ls += lpart[(long)s2 * M + m];
      short4 v = ((const short4*)hb)[(long)s2 * M * 128 + m * 128 + c4];
      ax += bf2f(v.x); ay += bf2f(v.y); az += bf2f(v.z); aw += bf2f(v.w);
    }
    float iv = 1.f / ls;
    return (float4){ax * iv, ay * iv, az * iv, aw * iv};
  };
  for (int j = 0; j < 16; ++j) {
    int n = n0 + j;
    long e = ((long)b * N + n) * 128 + c4;
    float coords = ((float)n + 0.5f) * scale - 0.5f;
    coords = fminf(fmaxf(coords, 0.f), (float)(pn - 1));
    int i0 = (int)coords;
    int i1 = min(i0 + 1, pn - 1);
    float wq = coords - (float)i0, ow = 1.f - wq;
    float4 hh0, hh1;
    if (KS == 1) {
      short4 h0 = ((const short4*)hb)[((long)b * pn + i0) * 128 + c4];
      short4 h1 = ((const short4*)hb)[((long)b * pn + i1) * 128 + c4];
      hh0 = (float4){bf2f(h0.x), bf2f(h0.y), bf2f(h0.z), bf2f(h0.w)};
      hh1 = (float4){bf2f(h1.x), bf2f(h1.y), bf2f(h1.z), bf2f(h1.w)};
    } else {
      if (i0 != cache_i0) {
        ch0 = (i0 == cache_i1) ? ch1 : comb(i0);
        cache_i0 = i0;
      }
      if (i1 != cache_i1) {
        ch1 = (i1 == i0) ? ch0 : comb(i1);
        cache_i1 = i1;
      }
      hh0 = ch0;
      hh1 = ch1;
    }
    short4 fv = ((const short4*)fbf)[e];
    float fhx, fhy, fhz, fhw;
    if (first) {
      fhx = fhy = fhz = fhw = 0.f;
    } else {
      short4 p = ((const short4*)fhin)[e];
      fhx = bf2f(p.x); fhy = bf2f(p.y); fhz = bf2f(p.z); fhw = bf2f(p.w);
    }
    fhx += hh0.x * ow + hh1.x * wq;
    fhy += hh0.y * ow + hh1.y * wq;
    fhz += hh0.z * ow + hh1.z * wq;
    fhw += hh0.w * ow + hh1.w * wq;
    if (last) {
      float4 o = {fhx, fhy, fhz, fhw};
      ((float4*)outf)[e] = o;
    } else {
      short4 o = {f2bf(fhx), f2bf(fhy), f2bf(fhz), f2bf(fhw)};
      ((short4*)fhout)[e] = o;
    }
    float dx = fhx - bf2f(fv.x), dy = fhy - bf2f(fv.y);
    float dz = fhz - bf2f(fv.z), dw = fhw - bf2f(fv.w);
    part += dx * dx + dy * dy + dz * dz + dw * dw;
    zx -= dx; zy -= dy; zz -= dz; zw -= dw;
    if (pn_next >= 64) {
      if (((n + 1) & (bs_next - 1)) == 0) {
        float inv = 1.f / (float)bs_next;
        *(u32*)&zq[((long)b * pn_next + n / bs_next) * C + c4 * 4] =
            pk4_fp8(zx * inv, zy * inv, zz * inv, zw * inv);
        zx = zy = zz = zw = 0.f;
      }
    }
  }
  if (pn_next && pn_next < 64) {
    float4 zp = {zx, zy, zz, zw};
    ((float4*)zpart)[((long)b * 64 + (n0 >> 4)) * 128 + c4] = zp;
  }
  __shared__ float red[256];
  red[threadIdx.x] = part;
  __syncthreads();
  for (int off = 128; off > 0; off >>= 1) {
    if (threadIdx.x < off) red[threadIdx.x] += red[threadIdx.x + off];
    __syncthreads();
  }
  if (threadIdx.x == 0) atomicAdd(&accum[blockIdx.x & 255], (double)red[0]);
}

// ---------------------------------------------------------------------------
__global__ void finalize_kernel(const double* __restrict__ accum,
                                float* __restrict__ out_scalars) {
  if (threadIdx.x == 0 && blockIdx.x == 0) {
    double s = 0.0;
    for (int i = 0; i < 256; ++i) s += accum[i];
    double denom = (double)SN * (double)BCN;
    out_scalars[0] = (float)(0.25 * s / denom);  // commit
    out_scalars[1] = (float)(s / denom);         // qlat
  }
}

// ---------------------------------------------------------------------------
extern "C" void kernel_launch(void* const* d_in, const int* in_sizes, int n_in,
                              void* d_out, int out_size, void* d_ws, size_t ws_size,
                              hipStream_t stream) {
  const float* f = (const float*)d_in[0];  // (B,N,C) fp32
  const float* W = (const float*)d_in[1];  // (K,C)  fp32
  float* out = (float*)d_out;

  const long MBy = 1l << 20;
  char* ws = (char*)d_ws;
  short* hb = (short*)ws;                              // 32 MB (h / bf16 partials)
  short* fbf = (short*)(ws + 32 * MBy);                // 32 MB
  short* fhbf = (short*)(ws + 64 * MBy);               // 32 MB
  unsigned char* zq = (unsigned char*)(ws + 96 * MBy); // 16 MB
  unsigned char* WnA = (unsigned char*)(ws + 112 * MBy);  // 2 MB
  unsigned char* WtB = (unsigned char*)(ws + 114 * MBy);  // 2 MB
  float* zpart = (float*)(ws + 116 * MBy);             // 4 MB region (uses 2)
  float* wsqf = (float*)(ws + 120 * MBy);              // 16 KB
  float* csum = (float*)(ws + 120 * MBy + (1l << 16)); // 64 KB
  float* lpart = (float*)(ws + 120 * MBy + (1l << 17)); // 128 KB
  double* accum = (double*)(ws + 121 * MBy);           // 2 KB

  hipMemsetAsync(accum, 0, 256 * sizeof(double), stream);

  wsq_kernel<<<K, 256, 0, stream>>>(W, wsqf);
  colsum_kernel<<<NCH, 256, 0, stream>>>(W, csum);
  prep_w<<<K / 32, 256, 0, stream>>>(W, WnA, WtB);
  init_f<<<B * 32, 256, 0, stream>>>(f, fbf, zpart);
  reduce_zpart<<<(B * 128 + 255) / 256, 256, 0, stream>>>(zpart, zq, 1);

  for (int s = 0; s < SN; ++s) {
    int pn = 1 << s;
    int M = B * pn;
    int gx = (M + 63) / 64;
    int KS = 512 / gx;
    if (KS < 1) KS = 1;
    if (KS > 32) KS = 32;
    flash_mfma<<<dim3(gx, KS), 256, 0, stream>>>(zq, WnA, WtB, wsqf, csum, hb, lpart, M, KS);
    int pn_next = (s < SN - 1) ? (pn << 1) : 0;
    fused_up<<<B * 32, 256, 0, stream>>>(hb, lpart, fbf, fhbf, fhbf, out, zq, zpart, accum,
                                         pn, pn_next, KS, s == 0 ? 1 : 0, s == SN - 1 ? 1 : 0);
    if (pn_next && pn_next < 64)
      reduce_zpart<<<(int)(((long)B * pn_next * 128 + 255) / 256), 256, 0, stream>>>(zpart, zq, pn_next);
  }

  finalize_kernel<<<1, 64, 0, stream>>>(accum, out + BCN);
}